// Round 7
// baseline (445.370 us; speedup 1.0000x reference)
//
#include <hip/hip_runtime.h>
#include <math.h>

// Problem constants. Device dtypes: all 12 inputs fp32, OUTPUT fp32.
#define BB 4
#define SS 4096
#define HH 8
#define DI 128
#define DOo 128
#define HD 1024        // HH*DI
#define NTOK (BB*SS)   // 16384
#define LNEPS 1e-6f

// cumsum chunking
#define CS1 64
#define NC1 64         // SS/CS1
// recurrence chunking
#define CS2 128
#define NC2 32         // SS/CS2

typedef unsigned short ubf;   // bf16 bits
typedef __attribute__((ext_vector_type(8))) short    bf16x8;
typedef __attribute__((ext_vector_type(8))) unsigned short u16x8;
typedef __attribute__((ext_vector_type(4))) unsigned short u16x4;
typedef __attribute__((ext_vector_type(4))) float    f32x4;

__device__ __forceinline__ float bf2f(ubf x) {
    union { unsigned int u; float f; } v; v.u = ((unsigned int)x) << 16; return v.f;
}
__device__ __forceinline__ ubf f2bf(float f) {
    union { float f; unsigned int u; } v; v.f = f;
    unsigned int r = v.u + 0x7FFFu + ((v.u >> 16) & 1u);   // RNE
    return (ubf)(r >> 16);
}
__device__ __forceinline__ float fast_sigmoid(float x) {
    return __builtin_amdgcn_rcpf(1.f + __expf(-x));
}
// async global->LDS, 16B per lane; lds ptr must be wave-uniform (dest = base + lane*16)
__device__ __forceinline__ void gload16(const ubf* g, ubf* l) {
    __builtin_amdgcn_global_load_lds(
        (const __attribute__((address_space(1))) void*)g,
        (__attribute__((address_space(3))) void*)l, 16, 0, 0);
}

// ---------------- block-wide reduction of two floats over blockDim.x (multiple of 64, <=1024)
__device__ __forceinline__ void blockReduce2(float& a, float& b, float2* scratch) {
    __syncthreads();
    int lane = threadIdx.x & 63;
    int wid  = threadIdx.x >> 6;
    #pragma unroll
    for (int off = 32; off > 0; off >>= 1) {
        a += __shfl_down(a, off);
        b += __shfl_down(b, off);
    }
    if (lane == 0) scratch[wid] = make_float2(a, b);
    __syncthreads();
    int nw = blockDim.x >> 6;
    if (wid == 0) {
        float2 v = (lane < nw) ? scratch[lane] : make_float2(0.f, 0.f);
        a = v.x; b = v.y;
        #pragma unroll
        for (int off = 8; off > 0; off >>= 1) {
            a += __shfl_down(a, off);
            b += __shfl_down(b, off);
        }
        if (lane == 0) scratch[0] = make_float2(a, b);
    }
    __syncthreads();
    float2 r = scratch[0];
    a = r.x; b = r.y;
}

// ---------------- KWT: W[h][256][NB] fp32 -> Wt[h][NB][256] bf16 (transpose for k-contiguous frags)
__global__ void kwt(const float* __restrict__ W, ubf* __restrict__ Wt, int NB) {
    int b = blockIdx.x;           // h*NB + n
    int h = b / NB, n = b % NB;
    int k = threadIdx.x;          // 0..255
    Wt[((size_t)h * NB + n) * 256 + k] = f2bf(W[((size_t)h * 256 + k) * NB + n]);
}

// ---------------- K1: per-chunk sums along S for the cumsum + emit in as bf16
__global__ void k1_chunksum(const float* __restrict__ in, float* __restrict__ chunk,
                            ubf* __restrict__ in_bf) {
    int bid = blockIdx.x;                 // b*HH*NC1 + h*NC1 + c
    int c = bid % NC1;
    int h = (bid / NC1) % HH;
    int b = bid / (NC1 * HH);
    int d = threadIdx.x;                  // 0..127
    size_t base = (size_t)(b * SS + c * CS1) * HD + h * DI + d;
    float s = 0.f;
    for (int i = 0; i < CS1; ++i) {
        float v = in[base + (size_t)i * HD];
        in_bf[base + (size_t)i * HD] = f2bf(v);
        s += v;
    }
    chunk[((b * NC1 + c) * HH + h) * DI + d] = s;
}

// ---------------- K2: serial exclusive scan over chunks (in-place)
__global__ void k2_chunkscan(float* __restrict__ chunk) {
    int bid = blockIdx.x;                 // b*HH + h
    int h = bid % HH;
    int b = bid / HH;
    int d = threadIdx.x;
    float run = 0.f;
    for (int c = 0; c < NC1; ++c) {
        int idx = ((b * NC1 + c) * HH + h) * DI + d;
        float v = chunk[idx];
        chunk[idx] = run;
        run += v;
    }
}

// ---------------- K3 (v2): in-chunk exclusive cumsum + LN over 1024/token.
// 256 threads x 4 dims (f32x4), wave butterfly + ONE barrier/token (parity-double-buffered
// scratch), next-token load prefetched before the barrier.
__global__ void __launch_bounds__(256) k3_csum_ln(
        const float* __restrict__ in, const float* __restrict__ chunkpre,
        const float* __restrict__ g, const float* __restrict__ beta,
        ubf* __restrict__ out) {
    __shared__ float2 scr[2][4];
    int c = blockIdx.x % NC1;
    int b = blockIdx.x / NC1;
    int t = threadIdx.x;                  // 0..255
    int lane = t & 63, w = t >> 6;
    int d0 = t * 4;
    f32x4 run = *(const f32x4*)(chunkpre + (size_t)(b * NC1 + c) * HD + d0);
    f32x4 gg  = *(const f32x4*)(g + d0);
    f32x4 bb  = *(const f32x4*)(beta + d0);
    const float* pin = in + (size_t)(b * SS + c * CS1) * HD + d0;
    ubf* pout = out + (size_t)(b * SS + c * CS1) * HD + d0;

    f32x4 v = *(const f32x4*)(pin);
    for (int i = 0; i < CS1; ++i) {
        f32x4 cs = run;
        run += v;
        float s = cs[0] + cs[1] + cs[2] + cs[3];
        float q = cs[0]*cs[0] + cs[1]*cs[1] + cs[2]*cs[2] + cs[3]*cs[3];
        #pragma unroll
        for (int off = 32; off >= 1; off >>= 1) {
            s += __shfl_xor(s, off);
            q += __shfl_xor(q, off);
        }
        if (lane == 0) scr[i & 1][w] = make_float2(s, q);
        // prefetch next token before the barrier (hides L2/L3 latency under sync)
        if (i + 1 < CS1) v = *(const f32x4*)(pin + (size_t)(i + 1) * HD);
        __syncthreads();
        float2 p0 = scr[i & 1][0], p1 = scr[i & 1][1];
        float2 p2 = scr[i & 1][2], p3 = scr[i & 1][3];
        float S = p0.x + p1.x + p2.x + p3.x;
        float Q = p0.y + p1.y + p2.y + p3.y;
        float mu = S * (1.f / 1024.f);
        float r = rsqrtf(Q * (1.f / 1024.f) - mu * mu + LNEPS);
        u16x4 o;
        #pragma unroll
        for (int e = 0; e < 4; ++e) o[e] = f2bf((cs[e] - mu) * r * gg[e] + bb[e]);
        *(u16x4*)(pout + (size_t)i * HD) = o;
    }
}

// ---------------- GEMM v6: m97-template + 2-phase double-buffer (T3 minimum recipe).
// 128x128 tile, BK=32, 4 waves, global_load_lds into fragment-packed LINEAR LDS (pre-swizzled
// per-lane global addresses; DMA dest = base+lane*16). Per iteration: STAGE(next) -> ds_read(cur)
// + 16 MFMA -> ONE __syncthreads (vmcnt(0)+barrier) -> flip. Stage latency hides under compute.
// MFMA swapped (mfma(bf, af)): reg quad runs along n -> u16x4 C stores.
// 1D grid + bijective XCD swizzle: each XCD owns one head (W slice L2-resident; n-tiles of a
// tok-tile adjacent for A L2-reuse). C col permuted: (n>>7)*1024 + h*128 + (n&127).
#define GSTAGE(BUF, KS)                                                                  \
    do {                                                                                 \
        int kks_ = (KS) * 32;                                                            \
        const ubf* Asrc_ = (kks_ < 128) ? Ab0 : Ab1;                                     \
        int kk_ = kks_ & 127;                                                            \
        _Pragma("unroll")                                                                \
        for (int cc_ = 0; cc_ < 2; ++cc_) {                                              \
            int mt_ = cc_ * 4 + w;                                                       \
            int row_ = mt_ * 16 + rl;                                                    \
            gload16(Asrc_ + (size_t)(tok0 + row_) * HD + h * DI + kk_ + kq * 8,          \
                    As[BUF] + (size_t)mt_ * 512);                                        \
            gload16(Wt + ((size_t)h * NB + n0 + row_) * 256 + kks_ + kq * 8,             \
                    Bs[BUF] + (size_t)mt_ * 512);                                        \
        }                                                                                \
    } while (0)

__global__ void __launch_bounds__(256) gemm_h(
        const ubf* __restrict__ Ab0, const ubf* __restrict__ Ab1,
        const ubf* __restrict__ Wt, const float* __restrict__ bias,
        ubf* __restrict__ C, int NB) {
    __shared__ __align__(16) ubf As[2][128 * 32];
    __shared__ __align__(16) ubf Bs[2][128 * 32];
    int t = threadIdx.x;
    int lane = t & 63, w = t >> 6;
    int ntiles = NB >> 7;                 // 3 (hid) or 1 (og)
    // bijective XCD swizzle (gridDim.x % 8 == 0): xcd-contiguous chunks, head = chunk owner
    int cpx = gridDim.x >> 3;
    int swz = (blockIdx.x & 7) * cpx + (blockIdx.x >> 3);
    int h   = swz / (128 * ntiles);
    int rem = swz - h * 128 * ntiles;
    int tok0 = (rem / ntiles) * 128;
    int n0   = (rem % ntiles) * 128;
    int crs = NB * HH;                    // C row stride

    f32x4 acc[4][4];
    #pragma unroll
    for (int i = 0; i < 4; ++i)
        #pragma unroll
        for (int j = 0; j < 4; ++j) acc[i][j] = (f32x4){0.f, 0.f, 0.f, 0.f};

    int rl = lane & 15, kq = lane >> 4;   // per-lane fragment coords

    GSTAGE(0, 0);
    __syncthreads();                      // drain prologue stage
    int cur = 0;
    #pragma unroll
    for (int ks = 0; ks < 8; ++ks) {
        if (ks < 7) GSTAGE(cur ^ 1, ks + 1);   // issue next-step loads BEFORE compute
        bf16x8 af[4], bf[4];
        #pragma unroll
        for (int i = 0; i < 4; ++i)
            af[i] = *(const bf16x8*)(As[cur] + (((w & 1) * 4 + i) * 64 + lane) * 8);
        #pragma unroll
        for (int j = 0; j < 4; ++j)
            bf[j] = *(const bf16x8*)(Bs[cur] + (((w >> 1) * 4 + j) * 64 + lane) * 8);
        #pragma unroll
        for (int i = 0; i < 4; ++i)
            #pragma unroll
            for (int j = 0; j < 4; ++j)
                acc[i][j] = __builtin_amdgcn_mfma_f32_16x16x32_bf16(bf[j], af[i], acc[i][j], 0, 0, 0);
        __syncthreads();                  // one barrier/iter: drains next-stage vmcnt + joins
        cur ^= 1;
    }

    // epilogue: n = n0+(w>>1)*64+j*16+(lane>>4)*4+r ; token = tok0+(w&1)*64+i*16+(lane&15)
    int nq0 = n0 + (w >> 1) * 64 + kq * 4;
    #pragma unroll
    for (int j = 0; j < 4; ++j) {
        int n = nq0 + j * 16;
        f32x4 bv = *(const f32x4*)(bias + h * NB + n);
        int col = (n >> 7) * 1024 + h * 128 + (n & 127);
        #pragma unroll
        for (int i = 0; i < 4; ++i) {
            u16x4 o;
            o[0] = f2bf(acc[i][j][0] + bv[0]);
            o[1] = f2bf(acc[i][j][1] + bv[1]);
            o[2] = f2bf(acc[i][j][2] + bv[2]);
            o[3] = f2bf(acc[i][j][3] + bv[3]);
            *(u16x4*)(C + (size_t)(tok0 + (w & 1) * 64 + i * 16 + rl) * crs + col) = o;
        }
    }
}

// ---------------- K4b (wave-per-token, 16384 waves): LN over 3072 (bias pre-folded in gemm), gates.
__global__ void __launch_bounds__(256, 4) k4b_ln_gates(
        const ubf* __restrict__ h3, const float* __restrict__ g,
        const float* __restrict__ beta, ubf* __restrict__ fgl, float* __restrict__ igh) {
    int lane = threadIdx.x & 63;
    int tok  = blockIdx.x * 4 + (threadIdx.x >> 6);
    int c0 = 8 * lane;                    // col base within a part-plane (q=1 adds 512)
    const ubf* p = h3 + (size_t)tok * 3072;

    u16x8 raw[6];
    #pragma unroll
    for (int pp = 0; pp < 3; ++pp) {
        raw[pp * 2 + 0] = *(const u16x8*)(p + pp * 1024 + c0);
        raw[pp * 2 + 1] = *(const u16x8*)(p + pp * 1024 + 512 + c0);
    }
    float sum = 0.f, sq = 0.f;
    #pragma unroll
    for (int s = 0; s < 6; ++s) {
        #pragma unroll
        for (int j = 0; j < 8; ++j) {
            float a = bf2f((ubf)raw[s][j]);
            sum += a; sq = fmaf(a, a, sq);
        }
    }
    #pragma unroll
    for (int m = 32; m >= 1; m >>= 1) {
        sum += __shfl_xor(sum, m);
        sq  += __shfl_xor(sq, m);
    }
    float mu = sum * (1.f / 3072.f);
    float r  = rsqrtf(sq * (1.f / 3072.f) - mu * mu + LNEPS);

    int dd = c0 & 127;
    size_t ob = (size_t)tok * HD + c0;
    #pragma unroll
    for (int q = 0; q < 2; ++q) {
        int hq = (c0 + q * 512) >> 7;
        int gb = hq * 384 + dd;           // g_hid/beta_hid are [h][part][d]
        f32x4 gv[3][2], bv[3][2];
        #pragma unroll
        for (int pp = 0; pp < 3; ++pp) {
            gv[pp][0] = *(const f32x4*)(g + gb + pp * 128);
            gv[pp][1] = *(const f32x4*)(g + gb + pp * 128 + 4);
            bv[pp][0] = *(const f32x4*)(beta + gb + pp * 128);
            bv[pp][1] = *(const f32x4*)(beta + gb + pp * 128 + 4);
        }
        u16x8 fo;
        f32x4 io0, io1;
        #pragma unroll
        for (int j = 0; j < 8; ++j) {
            float ai = bf2f((ubf)raw[0 + q][j]);
            float af = bf2f((ubf)raw[2 + q][j]);
            float ah = bf2f((ubf)raw[4 + q][j]);
            float li = (ai - mu) * r * gv[0][j >> 2][j & 3] + bv[0][j >> 2][j & 3];
            float lf = (af - mu) * r * gv[1][j >> 2][j & 3] + bv[1][j >> 2][j & 3];
            float lh = (ah - mu) * r * gv[2][j >> 2][j & 3] + bv[2][j >> 2][j & 3];
            fo[j] = f2bf(lf);
            float v = fast_sigmoid(li) * fmaxf(lh, 0.f);
            if (j < 4) io0[j & 3] = v; else io1[j & 3] = v;
        }
        *(u16x8*)(fgl + ob + q * 512) = fo;
        *(f32x4*)(igh + ob + q * 512) = io0;
        *(f32x4*)(igh + ob + q * 512 + 4) = io1;
    }
}

// ---------------- K5a: per-chunk recurrence summary: P = prod f, L = local end value
__global__ void k5a_chunkrec(const ubf* __restrict__ fgl, const float* __restrict__ igh,
                             float* __restrict__ Pb, float* __restrict__ Lb) {
    int bid = blockIdx.x;                 // b*NC2*HH + c*HH + h
    int h = bid % HH;
    int c = (bid / HH) % NC2;
    int b = bid / (HH * NC2);
    int d = threadIdx.x;
    size_t base = (size_t)(b * SS + c * CS2) * HD + h * DOo + d;
    float P = 1.f, L = 0.f;
    for (int s = 0; s < CS2; ++s) {
        float f = 1.f / (1.f + expf(-bf2f(fgl[base + (size_t)s * HD])));
        float i = igh[base + (size_t)s * HD];
        L = f * L + i;
        P *= f;
    }
    int o = ((b * NC2 + c) * HH + h) * DOo + d;
    Pb[o] = P;
    Lb[o] = L;
}

// ---------------- K5b: serial carry across chunks
__global__ void k5b_carry(const float* __restrict__ Pb, const float* __restrict__ Lb,
                          const float* __restrict__ init_cx, float* __restrict__ cIn) {
    int bid = blockIdx.x;                 // b*HH + h
    int h = bid % HH;
    int b = bid / HH;
    int d = threadIdx.x;
    float c = init_cx[h * DOo + d];
    for (int cc = 0; cc < NC2; ++cc) {
        int o = ((b * NC2 + cc) * HH + h) * DOo + d;
        cIn[o] = c;
        c = Pb[o] * c + Lb[o];
    }
}

// ---------------- K5c: final in-chunk recurrence; cell fp32 in-place over igh (d_out) + cell bf16 copy
__global__ void k5c_cell(const ubf* __restrict__ fgl, float* __restrict__ igh_cell,
                         const float* __restrict__ cIn, ubf* __restrict__ cell_bf) {
    int bid = blockIdx.x;
    int h = bid % HH;
    int c = (bid / HH) % NC2;
    int b = bid / (HH * NC2);
    int d = threadIdx.x;
    size_t base = (size_t)(b * SS + c * CS2) * HD + h * DOo + d;
    int o = ((b * NC2 + c) * HH + h) * DOo + d;
    float cv = cIn[o];
    for (int s = 0; s < CS2; ++s) {
        float f = 1.f / (1.f + expf(-bf2f(fgl[base + (size_t)s * HD])));
        float i = igh_cell[base + (size_t)s * HD];
        cv = f * cv + i;
        igh_cell[base + (size_t)s * HD] = cv;
        cell_bf[base + (size_t)s * HD] = f2bf(cv);
    }
}

// ---------------- K6b (wave-per-token): LN over 1024 (bias pre-folded in og gemm), sigmoid*cell -> out.
__global__ void __launch_bounds__(256, 4) k6b_ln_out(
        const ubf* __restrict__ ogr, float* __restrict__ out /* cell in, final out */,
        const float* __restrict__ g, const float* __restrict__ beta) {
    int lane = threadIdx.x & 63;
    int tok  = blockIdx.x * 4 + (threadIdx.x >> 6);
    int c0 = 8 * lane;
    size_t base = (size_t)tok * HD + c0;

    u16x8 og0 = *(const u16x8*)(ogr + base);
    u16x8 og1 = *(const u16x8*)(ogr + base + 512);
    f32x4 cl[2][2];
    cl[0][0] = *(const f32x4*)(out + base);
    cl[0][1] = *(const f32x4*)(out + base + 4);
    cl[1][0] = *(const f32x4*)(out + base + 512);
    cl[1][1] = *(const f32x4*)(out + base + 512 + 4);

    float sum = 0.f, sq = 0.f;
    #pragma unroll
    for (int j = 0; j < 8; ++j) {
        float a0 = bf2f((ubf)og0[j]);
        float a1 = bf2f((ubf)og1[j]);
        sum += a0 + a1;
        sq = fmaf(a0, a0, sq);
        sq = fmaf(a1, a1, sq);
    }
    #pragma unroll
    for (int m = 32; m >= 1; m >>= 1) {
        sum += __shfl_xor(sum, m);
        sq  += __shfl_xor(sq, m);
    }
    float mu = sum * (1.f / 1024.f);
    float r  = rsqrtf(sq * (1.f / 1024.f) - mu * mu + LNEPS);

    #pragma unroll
    for (int q = 0; q < 2; ++q) {
        f32x4 gv0 = *(const f32x4*)(g + q * 512 + c0);
        f32x4 gv1 = *(const f32x4*)(g + q * 512 + c0 + 4);
        f32x4 bv0 = *(const f32x4*)(beta + q * 512 + c0);
        f32x4 bv1 = *(const f32x4*)(beta + q * 512 + c0 + 4);
        f32x4 o0, o1;
        #pragma unroll
        for (int j = 0; j < 8; ++j) {
            float a = bf2f((ubf)(q ? og1[j] : og0[j]));
            float gg = (j < 4) ? gv0[j & 3] : gv1[j & 3];
            float bb = (j < 4) ? bv0[j & 3] : bv1[j & 3];
            float lo = (a - mu) * r * gg + bb;
            float v = fast_sigmoid(lo) * cl[q][j >> 2][j & 3];
            if (j < 4) o0[j & 3] = v; else o1[j & 3] = v;
        }
        *(f32x4*)(out + base + q * 512) = o0;
        *(f32x4*)(out + base + q * 512 + 4) = o1;
    }
}

extern "C" void kernel_launch(void* const* d_in, const int* in_sizes, int n_in,
                              void* d_out, int out_size, void* d_ws, size_t ws_size,
                              hipStream_t stream) {
    const float* heads_input = (const float*)d_in[0];
    const float* W_hid   = (const float*)d_in[1];
    const float* b_hid   = (const float*)d_in[2];
    const float* g_csum  = (const float*)d_in[3];
    const float* beta_csum = (const float*)d_in[4];
    const float* g_hid   = (const float*)d_in[5];
    const float* beta_hid = (const float*)d_in[6];
    const float* W_og    = (const float*)d_in[7];
    const float* b_og    = (const float*)d_in[8];
    const float* g_og    = (const float*)d_in[9];
    const float* beta_og = (const float*)d_in[10];
    const float* init_cx = (const float*)d_in[11];
    float* out = (float*)d_out;           // fp32 output, NTOK*HD elements

    // workspace layout (~172.5 MB)
    char* ws = (char*)d_ws;
    ubf* in_bf   = (ubf*)ws;                                   // 33,554,432 B
    ubf* csln_bf = (ubf*)(ws + (size_t)33554432);              // 33,554,432 B (later fgl)
    ubf* big     = (ubf*)(ws + (size_t)67108864);              // 100,663,296 B
    ubf* h3      = big;                                        // k4a w, k4b r
    ubf* cell_bf = big;                                        // k5c w, k6a r (h3 dead)
    ubf* og_bf   = big + (size_t)NTOK * HD;                    // k6a w, k6b r
    char* tail   = ws + (size_t)167772160;
    float* chunk = (float*)tail;                               // 1,048,576 B
    float* Pb    = chunk + (size_t)BB * NC1 * HD;              //   524,288 B
    float* Lb    = Pb + (size_t)BB * NC2 * HD;                 //   524,288 B
    float* cIn   = Lb + (size_t)BB * NC2 * HD;                 //   524,288 B
    ubf* Wt_hid  = (ubf*)(cIn + (size_t)BB * NC2 * HD);        // 1,572,864 B
    ubf* Wt_og   = Wt_hid + (size_t)HH * 384 * 256;            //   524,288 B
    ubf* fgl     = csln_bf;   // alias: csln consumed by gemm(k4a) before k4b writes fgl

    kwt<<<HH * 384, 256, 0, stream>>>(W_hid, Wt_hid, 384);
    kwt<<<HH * 128, 256, 0, stream>>>(W_og, Wt_og, 128);
    k1_chunksum<<<BB * HH * NC1, 128, 0, stream>>>(heads_input, chunk, in_bf);
    k2_chunkscan<<<BB * HH, 128, 0, stream>>>(chunk);
    k3_csum_ln<<<BB * NC1, 256, 0, stream>>>(heads_input, chunk, g_csum, beta_csum, csln_bf);
    gemm_h<<<(NTOK / 128) * 3 * HH, 256, 0, stream>>>(in_bf, csln_bf, Wt_hid, b_hid, h3, 384);
    k4b_ln_gates<<<NTOK / 4, 256, 0, stream>>>(h3, g_hid, beta_hid, fgl, out);
    k5a_chunkrec<<<BB * NC2 * HH, 128, 0, stream>>>(fgl, out, Pb, Lb);
    k5b_carry<<<BB * HH, 128, 0, stream>>>(Pb, Lb, init_cx, cIn);
    k5c_cell<<<BB * NC2 * HH, 128, 0, stream>>>(fgl, out, cIn, cell_bf);
    gemm_h<<<(NTOK / 128) * 1 * HH, 256, 0, stream>>>(in_bf, cell_bf, Wt_og, b_og, og_bf, 128);
    k6b_ln_out<<<NTOK / 4, 256, 0, stream>>>(og_bf, out, g_og, beta_og);
}

// Round 8
// 422.633 us; speedup vs baseline: 1.0538x; 1.0538x over previous
//
#include <hip/hip_runtime.h>
#include <math.h>

// Problem constants. Device dtypes: all 12 inputs fp32, OUTPUT fp32.
#define BB 4
#define SS 4096
#define HH 8
#define DI 128
#define DOo 128
#define HD 1024        // HH*DI
#define NTOK (BB*SS)   // 16384
#define LNEPS 1e-6f

// cumsum chunking
#define CS1 64
#define NC1 64         // SS/CS1
// recurrence chunking
#define CS2 128
#define NC2 32         // SS/CS2

typedef unsigned short ubf;   // bf16 bits
typedef __attribute__((ext_vector_type(8))) short    bf16x8;
typedef __attribute__((ext_vector_type(8))) unsigned short u16x8;
typedef __attribute__((ext_vector_type(4))) unsigned short u16x4;
typedef __attribute__((ext_vector_type(4))) float    f32x4;

__device__ __forceinline__ float bf2f(ubf x) {
    union { unsigned int u; float f; } v; v.u = ((unsigned int)x) << 16; return v.f;
}
__device__ __forceinline__ ubf f2bf(float f) {
    union { float f; unsigned int u; } v; v.f = f;
    unsigned int r = v.u + 0x7FFFu + ((v.u >> 16) & 1u);   // RNE
    return (ubf)(r >> 16);
}
__device__ __forceinline__ float fast_sigmoid(float x) {
    return __builtin_amdgcn_rcpf(1.f + __expf(-x));
}
// async global->LDS, 16B per lane; lds dest = wave-uniform base + lane*16, global src per-lane
__device__ __forceinline__ void gload16(const ubf* g, ubf* l) {
    __builtin_amdgcn_global_load_lds(
        (const __attribute__((address_space(1))) void*)g,
        (__attribute__((address_space(3))) void*)l, 16, 0, 0);
}

// ---------------- KWT_PACK: W[h][256][NB] fp32 -> Wtp in MFMA-fragment-linear order (bf16).
// Wtp[(((h*(NB/64)+ns)*8+ks)*4+j)*64+lane][8e]: a B-fragment load is base+lane*16B (1KB linear).
// n = ns*64+j*16+(lane&15), k = ks*32+(lane>>4)*8+e.  (v4-verified, R5 pass)
__global__ void kwt_pack(const float* __restrict__ W, ubf* __restrict__ Wtp, int NB) {
    int bid = blockIdx.x;                 // (h, ns, ks)
    int ks = bid & 7;
    int ns = (bid >> 3) % (NB >> 6);
    int h  = bid / (8 * (NB >> 6));
    int t = threadIdx.x;
    int j = t >> 6, lane = t & 63;
    int n  = ns * 64 + j * 16 + (lane & 15);
    int k0 = ks * 32 + (lane >> 4) * 8;
    u16x8 o;
    #pragma unroll
    for (int e = 0; e < 8; ++e)
        o[e] = f2bf(W[((size_t)h * 256 + k0 + e) * NB + n]);
    *(u16x8*)(Wtp + ((((size_t)(h * (NB >> 6) + ns) * 8 + ks) * 4 + j) * 64 + lane) * 8) = o;
}

// ---------------- K1: per-chunk sums along S for the cumsum + emit in as bf16
__global__ void k1_chunksum(const float* __restrict__ in, float* __restrict__ chunk,
                            ubf* __restrict__ in_bf) {
    int bid = blockIdx.x;                 // b*HH*NC1 + h*NC1 + c
    int c = bid % NC1;
    int h = (bid / NC1) % HH;
    int b = bid / (NC1 * HH);
    int d = threadIdx.x;                  // 0..127
    size_t base = (size_t)(b * SS + c * CS1) * HD + h * DI + d;
    float s = 0.f;
    for (int i = 0; i < CS1; ++i) {
        float v = in[base + (size_t)i * HD];
        in_bf[base + (size_t)i * HD] = f2bf(v);
        s += v;
    }
    chunk[((b * NC1 + c) * HH + h) * DI + d] = s;
}

// ---------------- K2: serial exclusive scan over chunks (in-place)
__global__ void k2_chunkscan(float* __restrict__ chunk) {
    int bid = blockIdx.x;                 // b*HH + h
    int h = bid % HH;
    int b = bid / HH;
    int d = threadIdx.x;
    float run = 0.f;
    for (int c = 0; c < NC1; ++c) {
        int idx = ((b * NC1 + c) * HH + h) * DI + d;
        float v = chunk[idx];
        chunk[idx] = run;
        run += v;
    }
}

// ---------------- K3 (v2): in-chunk exclusive cumsum + LN over 1024/token.
__global__ void __launch_bounds__(256) k3_csum_ln(
        const float* __restrict__ in, const float* __restrict__ chunkpre,
        const float* __restrict__ g, const float* __restrict__ beta,
        ubf* __restrict__ out) {
    __shared__ float2 scr[2][4];
    int c = blockIdx.x % NC1;
    int b = blockIdx.x / NC1;
    int t = threadIdx.x;                  // 0..255
    int lane = t & 63, w = t >> 6;
    int d0 = t * 4;
    f32x4 run = *(const f32x4*)(chunkpre + (size_t)(b * NC1 + c) * HD + d0);
    f32x4 gg  = *(const f32x4*)(g + d0);
    f32x4 bb  = *(const f32x4*)(beta + d0);
    const float* pin = in + (size_t)(b * SS + c * CS1) * HD + d0;
    ubf* pout = out + (size_t)(b * SS + c * CS1) * HD + d0;

    f32x4 v = *(const f32x4*)(pin);
    for (int i = 0; i < CS1; ++i) {
        f32x4 cs = run;
        run += v;
        float s = cs[0] + cs[1] + cs[2] + cs[3];
        float q = cs[0]*cs[0] + cs[1]*cs[1] + cs[2]*cs[2] + cs[3]*cs[3];
        #pragma unroll
        for (int off = 32; off >= 1; off >>= 1) {
            s += __shfl_xor(s, off);
            q += __shfl_xor(q, off);
        }
        if (lane == 0) scr[i & 1][w] = make_float2(s, q);
        if (i + 1 < CS1) v = *(const f32x4*)(pin + (size_t)(i + 1) * HD);
        __syncthreads();
        float2 p0 = scr[i & 1][0], p1 = scr[i & 1][1];
        float2 p2 = scr[i & 1][2], p3 = scr[i & 1][3];
        float S = p0.x + p1.x + p2.x + p3.x;
        float Q = p0.y + p1.y + p2.y + p3.y;
        float mu = S * (1.f / 1024.f);
        float r = rsqrtf(Q * (1.f / 1024.f) - mu * mu + LNEPS);
        u16x4 o;
        #pragma unroll
        for (int e = 0; e < 4; ++e) o[e] = f2bf((cs[e] - mu) * r * gg[e] + bb[e]);
        *(u16x4*)(pout + (size_t)i * HD) = o;
    }
}

// ---------------- GEMM v8: full-K A-tile staged ONCE into LDS (64KB, 1 barrier), then a
// BARRIER-FREE K/nt loop: af from LDS (conflict-mitigated XOR chunk swizzle), bf direct from
// packed Wtp (1KB linear, L2-hot), 16 MFMA per (nt,ks). No per-step vmcnt(0) drain -- the
// v5/v6/v7 invariant stall (MfmaUtil pinned 12.7%) was the per-K-step barrier drain.
// A LDS image: block bi=rowgrp*2+half (1KB) holds rows rowgrp*4..+3 of half (Ab0/Ab1),
//   lane l -> row rowgrp*4+(l>>4), chunk (l&15)^(l>>4). Read (r,c): byte =
//   ((r>>2)*2+(c>>4))*1024 + (r&3)*256 + ((c&15)^(r&3))*16.
// Fragment/lane mappings byte-identical to v6 (verified): af row=(w&1)*64+i*16+rl,
//   k=ks*32+kq*8; bf n=nt*128+(w>>1)*64+j*16+rl; mfma(bf,af); epilogue u16x4 unchanged.
// Grid 1D: h = bid&7 (== HW XCD round-robin -> W slice L2-resident per XCD).
__global__ void __launch_bounds__(256, 2) gemm_h(
        const ubf* __restrict__ Ab0, const ubf* __restrict__ Ab1,
        const ubf* __restrict__ Wtp, const float* __restrict__ bias,
        ubf* __restrict__ C, int NB) {
    __shared__ __align__(16) ubf As[64 * 512];   // 64 KB, full-K A-tile
    int t = threadIdx.x;
    int lane = t & 63, w = t >> 6;
    int h = blockIdx.x & 7;               // head == XCD
    int tok0 = (blockIdx.x >> 3) * 128;
    int ntiles = NB >> 7;                 // 3 (hid) or 1 (og)
    int crs = NB * HH;
    int rl = lane & 15, kq = lane >> 4;

    // ---- stage full-K A once: 64 instrs, each 4 rows x 256B contiguous (chunk-XOR preswizzled)
    {
        int rowi = lane >> 4;             // row within group
        int cg = (lane & 15) ^ rowi;      // swizzled 16B-chunk within half
        #pragma unroll
        for (int q = 0; q < 16; ++q) {
            int bi = w * 16 + q;
            int rowgrp = bi >> 1, half = bi & 1;
            int row = rowgrp * 4 + rowi;
            const ubf* src = (half ? Ab1 : Ab0)
                             + (size_t)(tok0 + row) * HD + h * DI + cg * 8;
            gload16(src, As + bi * 512);
        }
    }
    __syncthreads();   // the ONLY barrier: A resident + all DMAs drained

    const ubf* pWb = Wtp + ((size_t)h * (NB >> 6)) * 16384 + (size_t)lane * 8;

    for (int nt = 0; nt < ntiles; ++nt) {
        int ns = nt * 2 + (w >> 1);
        f32x4 acc[4][4];
        #pragma unroll
        for (int i = 0; i < 4; ++i)
            #pragma unroll
            for (int j = 0; j < 4; ++j) acc[i][j] = (f32x4){0.f, 0.f, 0.f, 0.f};

        #pragma unroll
        for (int ks = 0; ks < 8; ++ks) {
            bf16x8 bfr[4], af[4];
            #pragma unroll
            for (int j = 0; j < 4; ++j)
                bfr[j] = *(const bf16x8*)(pWb + (size_t)((ns * 8 + ks) * 4 + j) * 512);
            int c = ks * 4 + kq;
            int chi = (c >> 4) * 512;     // half select (bytes/2)
            int clo = ((c & 15) ^ (rl & 3)) * 8;
            #pragma unroll
            for (int i = 0; i < 4; ++i) {
                int r = (w & 1) * 64 + i * 16 + rl;
                af[i] = *(const bf16x8*)(As + ((r >> 2) * 2) * 512 + chi
                                            + (r & 3) * 128 + clo);
            }
            #pragma unroll
            for (int i = 0; i < 4; ++i)
                #pragma unroll
                for (int j = 0; j < 4; ++j)
                    acc[i][j] = __builtin_amdgcn_mfma_f32_16x16x32_bf16(bfr[j], af[i], acc[i][j], 0, 0, 0);
        }

        // epilogue: n = nt*128+(w>>1)*64+j*16+kq*4+r ; token = tok0+(w&1)*64+i*16+rl
        int nq0 = nt * 128 + (w >> 1) * 64 + kq * 4;
        #pragma unroll
        for (int j = 0; j < 4; ++j) {
            int n = nq0 + j * 16;
            f32x4 bv = *(const f32x4*)(bias + h * NB + n);
            int col = (n >> 7) * 1024 + h * 128 + (n & 127);
            #pragma unroll
            for (int i = 0; i < 4; ++i) {
                u16x4 o;
                o[0] = f2bf(acc[i][j][0] + bv[0]);
                o[1] = f2bf(acc[i][j][1] + bv[1]);
                o[2] = f2bf(acc[i][j][2] + bv[2]);
                o[3] = f2bf(acc[i][j][3] + bv[3]);
                *(u16x4*)(C + (size_t)(tok0 + (w & 1) * 64 + i * 16 + rl) * crs + col) = o;
            }
        }
    }
}

// ---------------- K4b (wave-per-token, 16384 waves): LN over 3072 (bias pre-folded in gemm), gates.
__global__ void __launch_bounds__(256, 4) k4b_ln_gates(
        const ubf* __restrict__ h3, const float* __restrict__ g,
        const float* __restrict__ beta, ubf* __restrict__ fgl, float* __restrict__ igh) {
    int lane = threadIdx.x & 63;
    int tok  = blockIdx.x * 4 + (threadIdx.x >> 6);
    int c0 = 8 * lane;                    // col base within a part-plane (q=1 adds 512)
    const ubf* p = h3 + (size_t)tok * 3072;

    u16x8 raw[6];
    #pragma unroll
    for (int pp = 0; pp < 3; ++pp) {
        raw[pp * 2 + 0] = *(const u16x8*)(p + pp * 1024 + c0);
        raw[pp * 2 + 1] = *(const u16x8*)(p + pp * 1024 + 512 + c0);
    }
    float sum = 0.f, sq = 0.f;
    #pragma unroll
    for (int s = 0; s < 6; ++s) {
        #pragma unroll
        for (int j = 0; j < 8; ++j) {
            float a = bf2f((ubf)raw[s][j]);
            sum += a; sq = fmaf(a, a, sq);
        }
    }
    #pragma unroll
    for (int m = 32; m >= 1; m >>= 1) {
        sum += __shfl_xor(sum, m);
        sq  += __shfl_xor(sq, m);
    }
    float mu = sum * (1.f / 3072.f);
    float r  = rsqrtf(sq * (1.f / 3072.f) - mu * mu + LNEPS);

    int dd = c0 & 127;
    size_t ob = (size_t)tok * HD + c0;
    #pragma unroll
    for (int q = 0; q < 2; ++q) {
        int hq = (c0 + q * 512) >> 7;
        int gb = hq * 384 + dd;           // g_hid/beta_hid are [h][part][d]
        f32x4 gv[3][2], bv[3][2];
        #pragma unroll
        for (int pp = 0; pp < 3; ++pp) {
            gv[pp][0] = *(const f32x4*)(g + gb + pp * 128);
            gv[pp][1] = *(const f32x4*)(g + gb + pp * 128 + 4);
            bv[pp][0] = *(const f32x4*)(beta + gb + pp * 128);
            bv[pp][1] = *(const f32x4*)(beta + gb + pp * 128 + 4);
        }
        u16x8 fo;
        f32x4 io0, io1;
        #pragma unroll
        for (int j = 0; j < 8; ++j) {
            float ai = bf2f((ubf)raw[0 + q][j]);
            float af = bf2f((ubf)raw[2 + q][j]);
            float ah = bf2f((ubf)raw[4 + q][j]);
            float li = (ai - mu) * r * gv[0][j >> 2][j & 3] + bv[0][j >> 2][j & 3];
            float lf = (af - mu) * r * gv[1][j >> 2][j & 3] + bv[1][j >> 2][j & 3];
            float lh = (ah - mu) * r * gv[2][j >> 2][j & 3] + bv[2][j >> 2][j & 3];
            fo[j] = f2bf(lf);
            float v = fast_sigmoid(li) * fmaxf(lh, 0.f);
            if (j < 4) io0[j & 3] = v; else io1[j & 3] = v;
        }
        *(u16x8*)(fgl + ob + q * 512) = fo;
        *(f32x4*)(igh + ob + q * 512) = io0;
        *(f32x4*)(igh + ob + q * 512 + 4) = io1;
    }
}

// ---------------- K5a: per-chunk recurrence summary: P = prod f, L = local end value
__global__ void k5a_chunkrec(const ubf* __restrict__ fgl, const float* __restrict__ igh,
                             float* __restrict__ Pb, float* __restrict__ Lb) {
    int bid = blockIdx.x;                 // b*NC2*HH + c*HH + h
    int h = bid % HH;
    int c = (bid / HH) % NC2;
    int b = bid / (HH * NC2);
    int d = threadIdx.x;
    size_t base = (size_t)(b * SS + c * CS2) * HD + h * DOo + d;
    float P = 1.f, L = 0.f;
    for (int s = 0; s < CS2; ++s) {
        float f = 1.f / (1.f + expf(-bf2f(fgl[base + (size_t)s * HD])));
        float i = igh[base + (size_t)s * HD];
        L = f * L + i;
        P *= f;
    }
    int o = ((b * NC2 + c) * HH + h) * DOo + d;
    Pb[o] = P;
    Lb[o] = L;
}

// ---------------- K5b: serial carry across chunks
__global__ void k5b_carry(const float* __restrict__ Pb, const float* __restrict__ Lb,
                          const float* __restrict__ init_cx, float* __restrict__ cIn) {
    int bid = blockIdx.x;                 // b*HH + h
    int h = bid % HH;
    int b = bid / HH;
    int d = threadIdx.x;
    float c = init_cx[h * DOo + d];
    for (int cc = 0; cc < NC2; ++cc) {
        int o = ((b * NC2 + cc) * HH + h) * DOo + d;
        cIn[o] = c;
        c = Pb[o] * c + Lb[o];
    }
}

// ---------------- K5c: final in-chunk recurrence; cell fp32 in-place over igh (d_out) + cell bf16 copy
__global__ void k5c_cell(const ubf* __restrict__ fgl, float* __restrict__ igh_cell,
                         const float* __restrict__ cIn, ubf* __restrict__ cell_bf) {
    int bid = blockIdx.x;
    int h = bid % HH;
    int c = (bid / HH) % NC2;
    int b = bid / (HH * NC2);
    int d = threadIdx.x;
    size_t base = (size_t)(b * SS + c * CS2) * HD + h * DOo + d;
    int o = ((b * NC2 + c) * HH + h) * DOo + d;
    float cv = cIn[o];
    for (int s = 0; s < CS2; ++s) {
        float f = 1.f / (1.f + expf(-bf2f(fgl[base + (size_t)s * HD])));
        float i = igh_cell[base + (size_t)s * HD];
        cv = f * cv + i;
        igh_cell[base + (size_t)s * HD] = cv;
        cell_bf[base + (size_t)s * HD] = f2bf(cv);
    }
}

// ---------------- K6b (wave-per-token): LN over 1024 (bias pre-folded in og gemm), sigmoid*cell -> out.
__global__ void __launch_bounds__(256, 4) k6b_ln_out(
        const ubf* __restrict__ ogr, float* __restrict__ out /* cell in, final out */,
        const float* __restrict__ g, const float* __restrict__ beta) {
    int lane = threadIdx.x & 63;
    int tok  = blockIdx.x * 4 + (threadIdx.x >> 6);
    int c0 = 8 * lane;
    size_t base = (size_t)tok * HD + c0;

    u16x8 og0 = *(const u16x8*)(ogr + base);
    u16x8 og1 = *(const u16x8*)(ogr + base + 512);
    f32x4 cl[2][2];
    cl[0][0] = *(const f32x4*)(out + base);
    cl[0][1] = *(const f32x4*)(out + base + 4);
    cl[1][0] = *(const f32x4*)(out + base + 512);
    cl[1][1] = *(const f32x4*)(out + base + 512 + 4);

    float sum = 0.f, sq = 0.f;
    #pragma unroll
    for (int j = 0; j < 8; ++j) {
        float a0 = bf2f((ubf)og0[j]);
        float a1 = bf2f((ubf)og1[j]);
        sum += a0 + a1;
        sq = fmaf(a0, a0, sq);
        sq = fmaf(a1, a1, sq);
    }
    #pragma unroll
    for (int m = 32; m >= 1; m >>= 1) {
        sum += __shfl_xor(sum, m);
        sq  += __shfl_xor(sq, m);
    }
    float mu = sum * (1.f / 1024.f);
    float r  = rsqrtf(sq * (1.f / 1024.f) - mu * mu + LNEPS);

    #pragma unroll
    for (int q = 0; q < 2; ++q) {
        f32x4 gv0 = *(const f32x4*)(g + q * 512 + c0);
        f32x4 gv1 = *(const f32x4*)(g + q * 512 + c0 + 4);
        f32x4 bv0 = *(const f32x4*)(beta + q * 512 + c0);
        f32x4 bv1 = *(const f32x4*)(beta + q * 512 + c0 + 4);
        f32x4 o0, o1;
        #pragma unroll
        for (int j = 0; j < 8; ++j) {
            float a = bf2f((ubf)(q ? og1[j] : og0[j]));
            float gg = (j < 4) ? gv0[j & 3] : gv1[j & 3];
            float bb = (j < 4) ? bv0[j & 3] : bv1[j & 3];
            float lo = (a - mu) * r * gg + bb;
            float v = fast_sigmoid(lo) * cl[q][j >> 2][j & 3];
            if (j < 4) o0[j & 3] = v; else o1[j & 3] = v;
        }
        *(f32x4*)(out + base + q * 512) = o0;
        *(f32x4*)(out + base + q * 512 + 4) = o1;
    }
}

extern "C" void kernel_launch(void* const* d_in, const int* in_sizes, int n_in,
                              void* d_out, int out_size, void* d_ws, size_t ws_size,
                              hipStream_t stream) {
    const float* heads_input = (const float*)d_in[0];
    const float* W_hid   = (const float*)d_in[1];
    const float* b_hid   = (const float*)d_in[2];
    const float* g_csum  = (const float*)d_in[3];
    const float* beta_csum = (const float*)d_in[4];
    const float* g_hid   = (const float*)d_in[5];
    const float* beta_hid = (const float*)d_in[6];
    const float* W_og    = (const float*)d_in[7];
    const float* b_og    = (const float*)d_in[8];
    const float* g_og    = (const float*)d_in[9];
    const float* beta_og = (const float*)d_in[10];
    const float* init_cx = (const float*)d_in[11];
    float* out = (float*)d_out;           // fp32 output, NTOK*HD elements

    // workspace layout (~172.5 MB)
    char* ws = (char*)d_ws;
    ubf* in_bf   = (ubf*)ws;                                   // 33,554,432 B
    ubf* csln_bf = (ubf*)(ws + (size_t)33554432);              // 33,554,432 B (later fgl)
    ubf* big     = (ubf*)(ws + (size_t)67108864);              // 100,663,296 B
    ubf* h3      = big;                                        // k4a w, k4b r
    ubf* cell_bf = big;                                        // k5c w, k6a r (h3 dead)
    ubf* og_bf   = big + (size_t)NTOK * HD;                    // k6a w, k6b r
    char* tail   = ws + (size_t)167772160;
    float* chunk = (float*)tail;                               // 1,048,576 B
    float* Pb    = chunk + (size_t)BB * NC1 * HD;              //   524,288 B
    float* Lb    = Pb + (size_t)BB * NC2 * HD;                 //   524,288 B
    float* cIn   = Lb + (size_t)BB * NC2 * HD;                 //   524,288 B
    ubf* Wt_hid  = (ubf*)(cIn + (size_t)BB * NC2 * HD);        // 1,572,864 B (packed)
    ubf* Wt_og   = Wt_hid + (size_t)HH * 384 * 256;            //   524,288 B (packed)
    ubf* fgl     = csln_bf;   // alias: csln consumed by gemm(k4a) before k4b writes fgl

    kwt_pack<<<HH * (384 >> 6) * 8, 256, 0, stream>>>(W_hid, Wt_hid, 384);
    kwt_pack<<<HH * (128 >> 6) * 8, 256, 0, stream>>>(W_og, Wt_og, 128);
    k1_chunksum<<<BB * HH * NC1, 128, 0, stream>>>(heads_input, chunk, in_bf);
    k2_chunkscan<<<BB * HH, 128, 0, stream>>>(chunk);
    k3_csum_ln<<<BB * NC1, 256, 0, stream>>>(heads_input, chunk, g_csum, beta_csum, csln_bf);
    gemm_h<<<(NTOK / 128) * HH, 256, 0, stream>>>(in_bf, csln_bf, Wt_hid, b_hid, h3, 384);
    k4b_ln_gates<<<NTOK / 4, 256, 0, stream>>>(h3, g_hid, beta_hid, fgl, out);
    k5a_chunkrec<<<BB * NC2 * HH, 128, 0, stream>>>(fgl, out, Pb, Lb);
    k5b_carry<<<BB * HH, 128, 0, stream>>>(Pb, Lb, init_cx, cIn);
    k5c_cell<<<BB * NC2 * HH, 128, 0, stream>>>(fgl, out, cIn, cell_bf);
    gemm_h<<<(NTOK / 128) * HH, 256, 0, stream>>>(in_bf, cell_bf, Wt_og, b_og, og_bf, 128);
    k6b_ln_out<<<NTOK / 4, 256, 0, stream>>>(og_bf, out, g_og, beta_og);
}

// Round 9
// 407.582 us; speedup vs baseline: 1.0927x; 1.0369x over previous
//
#include <hip/hip_runtime.h>
#include <math.h>

// Problem constants. Device dtypes: all 12 inputs fp32, OUTPUT fp32.
#define BB 4
#define SS 4096
#define HH 8
#define DI 128
#define DOo 128
#define HD 1024        // HH*DI
#define NTOK (BB*SS)   // 16384
#define LNEPS 1e-6f

// cumsum chunking
#define CS1 32
#define NC1 128        // SS/CS1
// recurrence chunking
#define CS2 128
#define NC2 32         // SS/CS2

typedef unsigned short ubf;   // bf16 bits
typedef __attribute__((ext_vector_type(8))) short    bf16x8;
typedef __attribute__((ext_vector_type(8))) unsigned short u16x8;
typedef __attribute__((ext_vector_type(4))) unsigned short u16x4;
typedef __attribute__((ext_vector_type(4))) float    f32x4;

__device__ __forceinline__ float bf2f(ubf x) {
    union { unsigned int u; float f; } v; v.u = ((unsigned int)x) << 16; return v.f;
}
__device__ __forceinline__ ubf f2bf(float f) {
    union { float f; unsigned int u; } v; v.f = f;
    unsigned int r = v.u + 0x7FFFu + ((v.u >> 16) & 1u);   // RNE
    return (ubf)(r >> 16);
}
__device__ __forceinline__ float fast_sigmoid(float x) {
    return __builtin_amdgcn_rcpf(1.f + __expf(-x));
}
// async global->LDS, 16B per lane; lds dest = wave-uniform base + lane*16, global src per-lane
__device__ __forceinline__ void gload16(const ubf* g, ubf* l) {
    __builtin_amdgcn_global_load_lds(
        (const __attribute__((address_space(1))) void*)g,
        (__attribute__((address_space(3))) void*)l, 16, 0, 0);
}

// ---------------- KWT_PACK: W[h][256][NB] fp32 -> Wtp in MFMA-fragment-linear order (bf16).
// Wtp[(((h*(NB/64)+ns)*8+ks)*4+j)*64+lane][8e]: a B-fragment load is base+lane*16B (1KB linear).
// n = ns*64+j*16+(lane&15), k = ks*32+(lane>>4)*8+e.  (v4-verified)
__global__ void kwt_pack(const float* __restrict__ W, ubf* __restrict__ Wtp, int NB) {
    int bid = blockIdx.x;                 // (h, ns, ks)
    int ks = bid & 7;
    int ns = (bid >> 3) % (NB >> 6);
    int h  = bid / (8 * (NB >> 6));
    int t = threadIdx.x;
    int j = t >> 6, lane = t & 63;
    int n  = ns * 64 + j * 16 + (lane & 15);
    int k0 = ks * 32 + (lane >> 4) * 8;
    u16x8 o;
    #pragma unroll
    for (int e = 0; e < 8; ++e)
        o[e] = f2bf(W[((size_t)h * 256 + k0 + e) * NB + n]);
    *(u16x8*)(Wtp + ((((size_t)(h * (NB >> 6) + ns) * 8 + ks) * 4 + j) * 64 + lane) * 8) = o;
}

// ---------------- K1: per-chunk sums along S for the cumsum + emit in as bf16
__global__ void k1_chunksum(const float* __restrict__ in, float* __restrict__ chunk,
                            ubf* __restrict__ in_bf) {
    int bid = blockIdx.x;                 // b*HH*NC1 + h*NC1 + c
    int c = bid % NC1;
    int h = (bid / NC1) % HH;
    int b = bid / (NC1 * HH);
    int d = threadIdx.x;                  // 0..127
    size_t base = (size_t)(b * SS + c * CS1) * HD + h * DI + d;
    float s = 0.f;
    for (int i = 0; i < CS1; ++i) {
        float v = in[base + (size_t)i * HD];
        in_bf[base + (size_t)i * HD] = f2bf(v);
        s += v;
    }
    chunk[((b * NC1 + c) * HH + h) * DI + d] = s;
}

// ---------------- K2: serial exclusive scan over chunks (in-place), batch-loaded 16-deep
// so the dependent-latency chain becomes 8 batches instead of 128 serial loads.
__global__ void k2_chunkscan(float* __restrict__ chunk) {
    int bid = blockIdx.x;                 // b*HH + h
    int h = bid % HH;
    int b = bid / HH;
    int d = threadIdx.x;
    float run = 0.f;
    for (int c0 = 0; c0 < NC1; c0 += 16) {
        float v[16];
        #pragma unroll
        for (int k = 0; k < 16; ++k)
            v[k] = chunk[((b * NC1 + c0 + k) * HH + h) * DI + d];
        #pragma unroll
        for (int k = 0; k < 16; ++k) {
            int idx = ((b * NC1 + c0 + k) * HH + h) * DI + d;
            chunk[idx] = run;
            run += v[k];
        }
    }
}

// ---------------- K3 (v2): in-chunk exclusive cumsum + LN over 1024/token (CS1=32 iters).
__global__ void __launch_bounds__(256) k3_csum_ln(
        const float* __restrict__ in, const float* __restrict__ chunkpre,
        const float* __restrict__ g, const float* __restrict__ beta,
        ubf* __restrict__ out) {
    __shared__ float2 scr[2][4];
    int c = blockIdx.x % NC1;
    int b = blockIdx.x / NC1;
    int t = threadIdx.x;                  // 0..255
    int lane = t & 63, w = t >> 6;
    int d0 = t * 4;
    f32x4 run = *(const f32x4*)(chunkpre + (size_t)(b * NC1 + c) * HD + d0);
    f32x4 gg  = *(const f32x4*)(g + d0);
    f32x4 bb  = *(const f32x4*)(beta + d0);
    const float* pin = in + (size_t)(b * SS + c * CS1) * HD + d0;
    ubf* pout = out + (size_t)(b * SS + c * CS1) * HD + d0;

    f32x4 v = *(const f32x4*)(pin);
    for (int i = 0; i < CS1; ++i) {
        f32x4 cs = run;
        run += v;
        float s = cs[0] + cs[1] + cs[2] + cs[3];
        float q = cs[0]*cs[0] + cs[1]*cs[1] + cs[2]*cs[2] + cs[3]*cs[3];
        #pragma unroll
        for (int off = 32; off >= 1; off >>= 1) {
            s += __shfl_xor(s, off);
            q += __shfl_xor(q, off);
        }
        if (lane == 0) scr[i & 1][w] = make_float2(s, q);
        if (i + 1 < CS1) v = *(const f32x4*)(pin + (size_t)(i + 1) * HD);
        __syncthreads();
        float2 p0 = scr[i & 1][0], p1 = scr[i & 1][1];
        float2 p2 = scr[i & 1][2], p3 = scr[i & 1][3];
        float S = p0.x + p1.x + p2.x + p3.x;
        float Q = p0.y + p1.y + p2.y + p3.y;
        float mu = S * (1.f / 1024.f);
        float r = rsqrtf(Q * (1.f / 1024.f) - mu * mu + LNEPS);
        u16x4 o;
        #pragma unroll
        for (int e = 0; e < 4; ++e) o[e] = f2bf((cs[e] - mu) * r * gg[e] + bb[e]);
        *(u16x4*)(pout + (size_t)i * HD) = o;
    }
}

// ---------------- GEMM v9: full-K A-tile staged once (64KB, 1 barrier), barrier-free loop.
// vs v8: (1) NB is a TEMPLATE param -> nt fully unrolled, all 32 B-frags of an nt loaded
// up-front into regs (static idx; ~215 VGPR, free at the LDS-bound 2 waves/SIMD);
// (2) full XOR swizzle cg = (lane&15)^rowi^((rowgrp&3)<<2) on BOTH sides -> af ds_read_b128
// lands 2-way on banks (free) instead of 4-way.
// Mappings otherwise byte-identical to v8 (R8-verified): af r=(w&1)*64+i*16+rl, k=ks*32+kq*8;
// bf n=nt*128+(w>>1)*64+j*16+rl; mfma(bf,af); epilogue u16x4, col=(n>>7)*1024+h*128+(n&127).
template <int NB>
__global__ void __launch_bounds__(256, 2) gemm_h(
        const ubf* __restrict__ Ab0, const ubf* __restrict__ Ab1,
        const ubf* __restrict__ Wtp, const float* __restrict__ bias,
        ubf* __restrict__ C) {
    __shared__ __align__(16) ubf As[64 * 512];   // 64 KB, full-K A-tile
    constexpr int ntiles = NB >> 7;       // 3 (hid) or 1 (og)
    int t = threadIdx.x;
    int lane = t & 63, w = t >> 6;
    int h = blockIdx.x & 7;               // head == XCD round-robin
    int tok0 = (blockIdx.x >> 3) * 128;
    int crs = NB * HH;
    int rl = lane & 15, kq = lane >> 4;

    // ---- stage full-K A once (chunk-XOR preswizzled global source; linear DMA dest)
    {
        int rowi = lane >> 4;             // row within 4-row group
        #pragma unroll
        for (int q = 0; q < 16; ++q) {
            int bi = w * 16 + q;
            int rowgrp = bi >> 1, half = bi & 1;
            int row = rowgrp * 4 + rowi;
            int cg = (lane & 15) ^ rowi ^ ((rowgrp & 3) << 2);
            const ubf* src = (half ? Ab1 : Ab0)
                             + (size_t)(tok0 + row) * HD + h * DI + cg * 8;
            gload16(src, As + bi * 512);
        }
    }
    __syncthreads();   // the ONLY barrier

    const ubf* pWb = Wtp + ((size_t)h * (NB >> 6)) * 16384 + (size_t)lane * 8;

    #pragma unroll
    for (int nt = 0; nt < ntiles; ++nt) {
        int ns = nt * 2 + (w >> 1);
        // all B fragments of this nt up-front (32 x 1KB linear loads, L2-hot)
        bf16x8 bfr[8][4];
        #pragma unroll
        for (int ks = 0; ks < 8; ++ks)
            #pragma unroll
            for (int j = 0; j < 4; ++j)
                bfr[ks][j] = *(const bf16x8*)(pWb + (size_t)((ns * 8 + ks) * 4 + j) * 512);

        f32x4 acc[4][4];
        #pragma unroll
        for (int i = 0; i < 4; ++i)
            #pragma unroll
            for (int j = 0; j < 4; ++j) acc[i][j] = (f32x4){0.f, 0.f, 0.f, 0.f};

        #pragma unroll
        for (int ks = 0; ks < 8; ++ks) {
            int c = ks * 4 + kq;
            int chi = (c >> 4) * 512;     // half select (in ubf units: 1024B block /2)
            int clo = (((c & 15) ^ (rl & 3)) ^ (((rl >> 2) & 3) << 2)) * 8;
            bf16x8 af[4];
            #pragma unroll
            for (int i = 0; i < 4; ++i) {
                int r = (w & 1) * 64 + i * 16 + rl;
                af[i] = *(const bf16x8*)(As + ((r >> 2) * 2) * 512 + chi
                                            + (r & 3) * 128 + clo);
            }
            #pragma unroll
            for (int i = 0; i < 4; ++i)
                #pragma unroll
                for (int j = 0; j < 4; ++j)
                    acc[i][j] = __builtin_amdgcn_mfma_f32_16x16x32_bf16(bfr[ks][j], af[i], acc[i][j], 0, 0, 0);
        }

        // epilogue: n = nt*128+(w>>1)*64+j*16+kq*4+r ; token = tok0+(w&1)*64+i*16+rl
        int nq0 = nt * 128 + (w >> 1) * 64 + kq * 4;
        #pragma unroll
        for (int j = 0; j < 4; ++j) {
            int n = nq0 + j * 16;
            f32x4 bv = *(const f32x4*)(bias + h * NB + n);
            int col = (n >> 7) * 1024 + h * 128 + (n & 127);
            #pragma unroll
            for (int i = 0; i < 4; ++i) {
                u16x4 o;
                o[0] = f2bf(acc[i][j][0] + bv[0]);
                o[1] = f2bf(acc[i][j][1] + bv[1]);
                o[2] = f2bf(acc[i][j][2] + bv[2]);
                o[3] = f2bf(acc[i][j][3] + bv[3]);
                *(u16x4*)(C + (size_t)(tok0 + (w & 1) * 64 + i * 16 + rl) * crs + col) = o;
            }
        }
    }
}

// ---------------- K4b (wave-per-token, 16384 waves): LN over 3072 (bias pre-folded in gemm), gates.
__global__ void __launch_bounds__(256, 4) k4b_ln_gates(
        const ubf* __restrict__ h3, const float* __restrict__ g,
        const float* __restrict__ beta, ubf* __restrict__ fgl, float* __restrict__ igh) {
    int lane = threadIdx.x & 63;
    int tok  = blockIdx.x * 4 + (threadIdx.x >> 6);
    int c0 = 8 * lane;                    // col base within a part-plane (q=1 adds 512)
    const ubf* p = h3 + (size_t)tok * 3072;

    u16x8 raw[6];
    #pragma unroll
    for (int pp = 0; pp < 3; ++pp) {
        raw[pp * 2 + 0] = *(const u16x8*)(p + pp * 1024 + c0);
        raw[pp * 2 + 1] = *(const u16x8*)(p + pp * 1024 + 512 + c0);
    }
    float sum = 0.f, sq = 0.f;
    #pragma unroll
    for (int s = 0; s < 6; ++s) {
        #pragma unroll
        for (int j = 0; j < 8; ++j) {
            float a = bf2f((ubf)raw[s][j]);
            sum += a; sq = fmaf(a, a, sq);
        }
    }
    #pragma unroll
    for (int m = 32; m >= 1; m >>= 1) {
        sum += __shfl_xor(sum, m);
        sq  += __shfl_xor(sq, m);
    }
    float mu = sum * (1.f / 3072.f);
    float r  = rsqrtf(sq * (1.f / 3072.f) - mu * mu + LNEPS);

    int dd = c0 & 127;
    size_t ob = (size_t)tok * HD + c0;
    #pragma unroll
    for (int q = 0; q < 2; ++q) {
        int hq = (c0 + q * 512) >> 7;
        int gb = hq * 384 + dd;           // g_hid/beta_hid are [h][part][d]
        f32x4 gv[3][2], bv[3][2];
        #pragma unroll
        for (int pp = 0; pp < 3; ++pp) {
            gv[pp][0] = *(const f32x4*)(g + gb + pp * 128);
            gv[pp][1] = *(const f32x4*)(g + gb + pp * 128 + 4);
            bv[pp][0] = *(const f32x4*)(beta + gb + pp * 128);
            bv[pp][1] = *(const f32x4*)(beta + gb + pp * 128 + 4);
        }
        u16x8 fo;
        f32x4 io0, io1;
        #pragma unroll
        for (int j = 0; j < 8; ++j) {
            float ai = bf2f((ubf)raw[0 + q][j]);
            float af = bf2f((ubf)raw[2 + q][j]);
            float ah = bf2f((ubf)raw[4 + q][j]);
            float li = (ai - mu) * r * gv[0][j >> 2][j & 3] + bv[0][j >> 2][j & 3];
            float lf = (af - mu) * r * gv[1][j >> 2][j & 3] + bv[1][j >> 2][j & 3];
            float lh = (ah - mu) * r * gv[2][j >> 2][j & 3] + bv[2][j >> 2][j & 3];
            fo[j] = f2bf(lf);
            float v = fast_sigmoid(li) * fmaxf(lh, 0.f);
            if (j < 4) io0[j & 3] = v; else io1[j & 3] = v;
        }
        *(u16x8*)(fgl + ob + q * 512) = fo;
        *(f32x4*)(igh + ob + q * 512) = io0;
        *(f32x4*)(igh + ob + q * 512 + 4) = io1;
    }
}

// ---------------- K5a: per-chunk recurrence summary: P = prod f, L = local end value
__global__ void k5a_chunkrec(const ubf* __restrict__ fgl, const float* __restrict__ igh,
                             float* __restrict__ Pb, float* __restrict__ Lb) {
    int bid = blockIdx.x;                 // b*NC2*HH + c*HH + h
    int h = bid % HH;
    int c = (bid / HH) % NC2;
    int b = bid / (HH * NC2);
    int d = threadIdx.x;
    size_t base = (size_t)(b * SS + c * CS2) * HD + h * DOo + d;
    float P = 1.f, L = 0.f;
    for (int s = 0; s < CS2; ++s) {
        float f = 1.f / (1.f + expf(-bf2f(fgl[base + (size_t)s * HD])));
        float i = igh[base + (size_t)s * HD];
        L = f * L + i;
        P *= f;
    }
    int o = ((b * NC2 + c) * HH + h) * DOo + d;
    Pb[o] = P;
    Lb[o] = L;
}

// ---------------- K5b: serial carry across chunks (batch-loaded 8-deep)
__global__ void k5b_carry(const float* __restrict__ Pb, const float* __restrict__ Lb,
                          const float* __restrict__ init_cx, float* __restrict__ cIn) {
    int bid = blockIdx.x;                 // b*HH + h
    int h = bid % HH;
    int b = bid / HH;
    int d = threadIdx.x;
    float c = init_cx[h * DOo + d];
    for (int c0 = 0; c0 < NC2; c0 += 8) {
        float pv[8], lv[8];
        #pragma unroll
        for (int k = 0; k < 8; ++k) {
            int o = ((b * NC2 + c0 + k) * HH + h) * DOo + d;
            pv[k] = Pb[o];
            lv[k] = Lb[o];
        }
        #pragma unroll
        for (int k = 0; k < 8; ++k) {
            int o = ((b * NC2 + c0 + k) * HH + h) * DOo + d;
            cIn[o] = c;
            c = pv[k] * c + lv[k];
        }
    }
}

// ---------------- K5c: final in-chunk recurrence; cell fp32 in-place over igh (d_out) + cell bf16 copy
__global__ void k5c_cell(const ubf* __restrict__ fgl, float* __restrict__ igh_cell,
                         const float* __restrict__ cIn, ubf* __restrict__ cell_bf) {
    int bid = blockIdx.x;
    int h = bid % HH;
    int c = (bid / HH) % NC2;
    int b = bid / (HH * NC2);
    int d = threadIdx.x;
    size_t base = (size_t)(b * SS + c * CS2) * HD + h * DOo + d;
    int o = ((b * NC2 + c) * HH + h) * DOo + d;
    float cv = cIn[o];
    for (int s = 0; s < CS2; ++s) {
        float f = 1.f / (1.f + expf(-bf2f(fgl[base + (size_t)s * HD])));
        float i = igh_cell[base + (size_t)s * HD];
        cv = f * cv + i;
        igh_cell[base + (size_t)s * HD] = cv;
        cell_bf[base + (size_t)s * HD] = f2bf(cv);
    }
}

// ---------------- K6b (wave-per-token): LN over 1024 (bias pre-folded in og gemm), sigmoid*cell -> out.
__global__ void __launch_bounds__(256, 4) k6b_ln_out(
        const ubf* __restrict__ ogr, float* __restrict__ out /* cell in, final out */,
        const float* __restrict__ g, const float* __restrict__ beta) {
    int lane = threadIdx.x & 63;
    int tok  = blockIdx.x * 4 + (threadIdx.x >> 6);
    int c0 = 8 * lane;
    size_t base = (size_t)tok * HD + c0;

    u16x8 og0 = *(const u16x8*)(ogr + base);
    u16x8 og1 = *(const u16x8*)(ogr + base + 512);
    f32x4 cl[2][2];
    cl[0][0] = *(const f32x4*)(out + base);
    cl[0][1] = *(const f32x4*)(out + base + 4);
    cl[1][0] = *(const f32x4*)(out + base + 512);
    cl[1][1] = *(const f32x4*)(out + base + 512 + 4);

    float sum = 0.f, sq = 0.f;
    #pragma unroll
    for (int j = 0; j < 8; ++j) {
        float a0 = bf2f((ubf)og0[j]);
        float a1 = bf2f((ubf)og1[j]);
        sum += a0 + a1;
        sq = fmaf(a0, a0, sq);
        sq = fmaf(a1, a1, sq);
    }
    #pragma unroll
    for (int m = 32; m >= 1; m >>= 1) {
        sum += __shfl_xor(sum, m);
        sq  += __shfl_xor(sq, m);
    }
    float mu = sum * (1.f / 1024.f);
    float r  = rsqrtf(sq * (1.f / 1024.f) - mu * mu + LNEPS);

    #pragma unroll
    for (int q = 0; q < 2; ++q) {
        f32x4 gv0 = *(const f32x4*)(g + q * 512 + c0);
        f32x4 gv1 = *(const f32x4*)(g + q * 512 + c0 + 4);
        f32x4 bv0 = *(const f32x4*)(beta + q * 512 + c0);
        f32x4 bv1 = *(const f32x4*)(beta + q * 512 + c0 + 4);
        f32x4 o0, o1;
        #pragma unroll
        for (int j = 0; j < 8; ++j) {
            float a = bf2f((ubf)(q ? og1[j] : og0[j]));
            float gg = (j < 4) ? gv0[j & 3] : gv1[j & 3];
            float bb = (j < 4) ? bv0[j & 3] : bv1[j & 3];
            float lo = (a - mu) * r * gg + bb;
            float v = fast_sigmoid(lo) * cl[q][j >> 2][j & 3];
            if (j < 4) o0[j & 3] = v; else o1[j & 3] = v;
        }
        *(f32x4*)(out + base + q * 512) = o0;
        *(f32x4*)(out + base + q * 512 + 4) = o1;
    }
}

extern "C" void kernel_launch(void* const* d_in, const int* in_sizes, int n_in,
                              void* d_out, int out_size, void* d_ws, size_t ws_size,
                              hipStream_t stream) {
    const float* heads_input = (const float*)d_in[0];
    const float* W_hid   = (const float*)d_in[1];
    const float* b_hid   = (const float*)d_in[2];
    const float* g_csum  = (const float*)d_in[3];
    const float* beta_csum = (const float*)d_in[4];
    const float* g_hid   = (const float*)d_in[5];
    const float* beta_hid = (const float*)d_in[6];
    const float* W_og    = (const float*)d_in[7];
    const float* b_og    = (const float*)d_in[8];
    const float* g_og    = (const float*)d_in[9];
    const float* beta_og = (const float*)d_in[10];
    const float* init_cx = (const float*)d_in[11];
    float* out = (float*)d_out;           // fp32 output, NTOK*HD elements

    // workspace layout (~171.5 MB)
    char* ws = (char*)d_ws;
    ubf* in_bf   = (ubf*)ws;                                   // 33,554,432 B
    ubf* csln_bf = (ubf*)(ws + (size_t)33554432);              // 33,554,432 B (later fgl)
    ubf* big     = (ubf*)(ws + (size_t)67108864);              // 100,663,296 B
    float* chunk = (float*)big;   // 2MB, k1..k3 only; dead before gemm writes h3 here
    ubf* h3      = big;                                        // k4a w, k4b r
    ubf* cell_bf = big;                                        // k5c w, k6a r (h3 dead)
    ubf* og_bf   = big + (size_t)NTOK * HD;                    // k6a w, k6b r
    char* tail   = ws + (size_t)167772160;
    float* Pb    = (float*)tail;                               //   524,288 B
    float* Lb    = Pb + (size_t)BB * NC2 * HD;                 //   524,288 B
    float* cIn   = Lb + (size_t)BB * NC2 * HD;                 //   524,288 B
    ubf* Wt_hid  = (ubf*)(cIn + (size_t)BB * NC2 * HD);        // 1,572,864 B (packed)
    ubf* Wt_og   = Wt_hid + (size_t)HH * 384 * 256;            //   524,288 B (packed)
    ubf* fgl     = csln_bf;   // alias: csln consumed by gemm(k4a) before k4b writes fgl

    kwt_pack<<<HH * (384 >> 6) * 8, 256, 0, stream>>>(W_hid, Wt_hid, 384);
    kwt_pack<<<HH * (128 >> 6) * 8, 256, 0, stream>>>(W_og, Wt_og, 128);
    k1_chunksum<<<BB * HH * NC1, 128, 0, stream>>>(heads_input, chunk, in_bf);
    k2_chunkscan<<<BB * HH, 128, 0, stream>>>(chunk);
    k3_csum_ln<<<BB * NC1, 256, 0, stream>>>(heads_input, chunk, g_csum, beta_csum, csln_bf);
    gemm_h<384><<<(NTOK / 128) * HH, 256, 0, stream>>>(in_bf, csln_bf, Wt_hid, b_hid, h3);
    k4b_ln_gates<<<NTOK / 4, 256, 0, stream>>>(h3, g_hid, beta_hid, fgl, out);
    k5a_chunkrec<<<BB * NC2 * HH, 128, 0, stream>>>(fgl, out, Pb, Lb);
    k5b_carry<<<BB * HH, 128, 0, stream>>>(Pb, Lb, init_cx, cIn);
    k5c_cell<<<BB * NC2 * HH, 128, 0, stream>>>(fgl, out, cIn, cell_bf);
    gemm_h<128><<<(NTOK / 128) * HH, 256, 0, stream>>>(in_bf, cell_bf, Wt_og, b_og, og_bf);
    k6b_ln_out<<<NTOK / 4, 256, 0, stream>>>(og_bf, out, g_og, beta_og);
}

// Round 10
// 391.220 us; speedup vs baseline: 1.1384x; 1.0418x over previous
//
#include <hip/hip_runtime.h>
#include <math.h>

// Problem constants. Device dtypes: all 12 inputs fp32, OUTPUT fp32.
#define BB 4
#define SS 4096
#define HH 8
#define DI 128
#define DOo 128
#define HD 1024        // HH*DI
#define NTOK (BB*SS)   // 16384
#define LNEPS 1e-6f

// cumsum chunking
#define CS1 32
#define NC1 128        // SS/CS1
// recurrence chunking
#define CS2 128
#define NC2 32         // SS/CS2

typedef unsigned short ubf;   // bf16 bits
typedef __attribute__((ext_vector_type(8))) short    bf16x8;
typedef __attribute__((ext_vector_type(8))) unsigned short u16x8;
typedef __attribute__((ext_vector_type(4))) unsigned short u16x4;
typedef __attribute__((ext_vector_type(4))) float    f32x4;

__device__ __forceinline__ float bf2f(ubf x) {
    union { unsigned int u; float f; } v; v.u = ((unsigned int)x) << 16; return v.f;
}
__device__ __forceinline__ ubf f2bf(float f) {
    union { float f; unsigned int u; } v; v.f = f;
    unsigned int r = v.u + 0x7FFFu + ((v.u >> 16) & 1u);   // RNE
    return (ubf)(r >> 16);
}
__device__ __forceinline__ float fast_sigmoid(float x) {
    return __builtin_amdgcn_rcpf(1.f + __expf(-x));
}
// async global->LDS, 16B per lane; lds dest = wave-uniform base + lane*16, global src per-lane
__device__ __forceinline__ void gload16(const ubf* g, ubf* l) {
    __builtin_amdgcn_global_load_lds(
        (const __attribute__((address_space(1))) void*)g,
        (__attribute__((address_space(3))) void*)l, 16, 0, 0);
}

// ---------------- KWT_PACK: W[h][256][NB] fp32 -> Wtp in MFMA-fragment-linear order (bf16).
// Wtp[(((h*(NB/64)+ns)*8+ks)*4+j)*64+lane][8e]: a B-fragment load is base+lane*16B (1KB linear).
// n = ns*64+j*16+(lane&15), k = ks*32+(lane>>4)*8+e.  (v4-verified)
__global__ void kwt_pack(const float* __restrict__ W, ubf* __restrict__ Wtp, int NB) {
    int bid = blockIdx.x;                 // (h, ns, ks)
    int ks = bid & 7;
    int ns = (bid >> 3) % (NB >> 6);
    int h  = bid / (8 * (NB >> 6));
    int t = threadIdx.x;
    int j = t >> 6, lane = t & 63;
    int n  = ns * 64 + j * 16 + (lane & 15);
    int k0 = ks * 32 + (lane >> 4) * 8;
    u16x8 o;
    #pragma unroll
    for (int e = 0; e < 8; ++e)
        o[e] = f2bf(W[((size_t)h * 256 + k0 + e) * NB + n]);
    *(u16x8*)(Wtp + ((((size_t)(h * (NB >> 6) + ns) * 8 + ks) * 4 + j) * 64 + lane) * 8) = o;
}

// ---------------- K1: per-chunk sums along S for the cumsum + emit in as bf16
__global__ void k1_chunksum(const float* __restrict__ in, float* __restrict__ chunk,
                            ubf* __restrict__ in_bf) {
    int bid = blockIdx.x;                 // b*HH*NC1 + h*NC1 + c
    int c = bid % NC1;
    int h = (bid / NC1) % HH;
    int b = bid / (NC1 * HH);
    int d = threadIdx.x;                  // 0..127
    size_t base = (size_t)(b * SS + c * CS1) * HD + h * DI + d;
    float s = 0.f;
    for (int i = 0; i < CS1; ++i) {
        float v = in[base + (size_t)i * HD];
        in_bf[base + (size_t)i * HD] = f2bf(v);
        s += v;
    }
    chunk[((b * NC1 + c) * HH + h) * DI + d] = s;
}

// ---------------- K2: serial exclusive scan over chunks (in-place), batch-loaded 16-deep
__global__ void k2_chunkscan(float* __restrict__ chunk) {
    int bid = blockIdx.x;                 // b*HH + h
    int h = bid % HH;
    int b = bid / HH;
    int d = threadIdx.x;
    float run = 0.f;
    for (int c0 = 0; c0 < NC1; c0 += 16) {
        float v[16];
        #pragma unroll
        for (int k = 0; k < 16; ++k)
            v[k] = chunk[((b * NC1 + c0 + k) * HH + h) * DI + d];
        #pragma unroll
        for (int k = 0; k < 16; ++k) {
            int idx = ((b * NC1 + c0 + k) * HH + h) * DI + d;
            chunk[idx] = run;
            run += v[k];
        }
    }
}

// ---------------- K3 (v2): in-chunk exclusive cumsum + LN over 1024/token (CS1=32 iters).
__global__ void __launch_bounds__(256) k3_csum_ln(
        const float* __restrict__ in, const float* __restrict__ chunkpre,
        const float* __restrict__ g, const float* __restrict__ beta,
        ubf* __restrict__ out) {
    __shared__ float2 scr[2][4];
    int c = blockIdx.x % NC1;
    int b = blockIdx.x / NC1;
    int t = threadIdx.x;                  // 0..255
    int lane = t & 63, w = t >> 6;
    int d0 = t * 4;
    f32x4 run = *(const f32x4*)(chunkpre + (size_t)(b * NC1 + c) * HD + d0);
    f32x4 gg  = *(const f32x4*)(g + d0);
    f32x4 bb  = *(const f32x4*)(beta + d0);
    const float* pin = in + (size_t)(b * SS + c * CS1) * HD + d0;
    ubf* pout = out + (size_t)(b * SS + c * CS1) * HD + d0;

    f32x4 v = *(const f32x4*)(pin);
    for (int i = 0; i < CS1; ++i) {
        f32x4 cs = run;
        run += v;
        float s = cs[0] + cs[1] + cs[2] + cs[3];
        float q = cs[0]*cs[0] + cs[1]*cs[1] + cs[2]*cs[2] + cs[3]*cs[3];
        #pragma unroll
        for (int off = 32; off >= 1; off >>= 1) {
            s += __shfl_xor(s, off);
            q += __shfl_xor(q, off);
        }
        if (lane == 0) scr[i & 1][w] = make_float2(s, q);
        if (i + 1 < CS1) v = *(const f32x4*)(pin + (size_t)(i + 1) * HD);
        __syncthreads();
        float2 p0 = scr[i & 1][0], p1 = scr[i & 1][1];
        float2 p2 = scr[i & 1][2], p3 = scr[i & 1][3];
        float S = p0.x + p1.x + p2.x + p3.x;
        float Q = p0.y + p1.y + p2.y + p3.y;
        float mu = S * (1.f / 1024.f);
        float r = rsqrtf(Q * (1.f / 1024.f) - mu * mu + LNEPS);
        u16x4 o;
        #pragma unroll
        for (int e = 0; e < 4; ++e) o[e] = f2bf((cs[e] - mu) * r * gg[e] + bb[e]);
        *(u16x4*)(pout + (size_t)i * HD) = o;
    }
}

// ---------------- GEMM v10: 64-token blocks, full-K A-tile 32KB (1 barrier), barrier-free loop.
// vs v9: halved tok-tile -> 32KB LDS -> 4 blocks/CU resident (launch_bounds(256,4), VGPR<=128)
// so stage/compute/store phases of different blocks overlap (v9's 61us = serialized phases at
// 2 blocks/CU). acc[2][4]/wave; B 2-deep ping-pong (compiler-scheduled, L2-hot 1KB linear).
// Mappings = R8/R9-verified pair, r = wm*32+i*16+rl (XOR formula invariant: (r>>2)&3 == rl>>2).
// Stage: 32 bi-blocks, bi=w*8+q; read af byte = ((r>>2)*2+(c>>4))*1024+(r&3)*256+clo*16,
//   clo = (c&15)^(rl&3)^((rl>>2)<<2).  mfma(bf,af); epilogue u16x4, col=(n>>7)*1024+h*128+(n&127).
template <int NB>
__global__ void __launch_bounds__(256, 4) gemm_h(
        const ubf* __restrict__ Ab0, const ubf* __restrict__ Ab1,
        const ubf* __restrict__ Wtp, const float* __restrict__ bias,
        ubf* __restrict__ C) {
    __shared__ __align__(16) ubf As[32 * 512];   // 32 KB, full-K A-tile for 64 tokens
    constexpr int ntiles = NB >> 7;       // 3 (hid) or 1 (og)
    int t = threadIdx.x;
    int lane = t & 63, w = t >> 6;
    int h = blockIdx.x & 7;               // head == XCD round-robin
    int tok0 = (blockIdx.x >> 3) * 64;
    int crs = NB * HH;
    int rl = lane & 15, kq = lane >> 4;
    int wm = w & 1, wn = w >> 1;

    // ---- stage full-K A once (chunk-XOR preswizzled global source; linear DMA dest)
    {
        int rowi = lane >> 4;             // row within 4-row group
        #pragma unroll
        for (int q = 0; q < 8; ++q) {
            int bi = w * 8 + q;
            int rowgrp = bi >> 1, half = bi & 1;
            int row = rowgrp * 4 + rowi;
            int cg = (lane & 15) ^ rowi ^ ((rowgrp & 3) << 2);
            const ubf* src = (half ? Ab1 : Ab0)
                             + (size_t)(tok0 + row) * HD + h * DI + cg * 8;
            gload16(src, As + bi * 512);
        }
    }
    __syncthreads();   // the ONLY barrier

    const ubf* pWb = Wtp + ((size_t)h * (NB >> 6)) * 16384 + (size_t)lane * 8;

    #pragma unroll
    for (int nt = 0; nt < ntiles; ++nt) {
        int ns = nt * 2 + wn;
        f32x4 acc[2][4];
        #pragma unroll
        for (int i = 0; i < 2; ++i)
            #pragma unroll
            for (int j = 0; j < 4; ++j) acc[i][j] = (f32x4){0.f, 0.f, 0.f, 0.f};

        bf16x8 b0[4], b1[4];
        #pragma unroll
        for (int j = 0; j < 4; ++j)
            b0[j] = *(const bf16x8*)(pWb + (size_t)((ns * 8 + 0) * 4 + j) * 512);
        #pragma unroll
        for (int j = 0; j < 4; ++j)
            b1[j] = *(const bf16x8*)(pWb + (size_t)((ns * 8 + 1) * 4 + j) * 512);

        #pragma unroll
        for (int ks = 0; ks < 8; ks += 2) {
            // compute ks with b0
            {
                int c = ks * 4 + kq;
                int chi = (c >> 4) * 512;
                int clo = ((c & 15) ^ (rl & 3) ^ ((rl >> 2) << 2)) * 8;
                bf16x8 af[2];
                #pragma unroll
                for (int i = 0; i < 2; ++i) {
                    int r = wm * 32 + i * 16 + rl;
                    af[i] = *(const bf16x8*)(As + ((r >> 2) * 2) * 512 + chi
                                                + (r & 3) * 128 + clo);
                }
                #pragma unroll
                for (int i = 0; i < 2; ++i)
                    #pragma unroll
                    for (int j = 0; j < 4; ++j)
                        acc[i][j] = __builtin_amdgcn_mfma_f32_16x16x32_bf16(b0[j], af[i], acc[i][j], 0, 0, 0);
            }
            if (ks + 2 < 8) {
                #pragma unroll
                for (int j = 0; j < 4; ++j)
                    b0[j] = *(const bf16x8*)(pWb + (size_t)((ns * 8 + ks + 2) * 4 + j) * 512);
            }
            // compute ks+1 with b1
            {
                int c = (ks + 1) * 4 + kq;
                int chi = (c >> 4) * 512;
                int clo = ((c & 15) ^ (rl & 3) ^ ((rl >> 2) << 2)) * 8;
                bf16x8 af[2];
                #pragma unroll
                for (int i = 0; i < 2; ++i) {
                    int r = wm * 32 + i * 16 + rl;
                    af[i] = *(const bf16x8*)(As + ((r >> 2) * 2) * 512 + chi
                                                + (r & 3) * 128 + clo);
                }
                #pragma unroll
                for (int i = 0; i < 2; ++i)
                    #pragma unroll
                    for (int j = 0; j < 4; ++j)
                        acc[i][j] = __builtin_amdgcn_mfma_f32_16x16x32_bf16(b1[j], af[i], acc[i][j], 0, 0, 0);
            }
            if (ks + 3 < 8) {
                #pragma unroll
                for (int j = 0; j < 4; ++j)
                    b1[j] = *(const bf16x8*)(pWb + (size_t)((ns * 8 + ks + 3) * 4 + j) * 512);
            }
        }

        // epilogue: n = nt*128+wn*64+j*16+kq*4+r ; token = tok0+wm*32+i*16+rl
        int nq0 = nt * 128 + wn * 64 + kq * 4;
        #pragma unroll
        for (int j = 0; j < 4; ++j) {
            int n = nq0 + j * 16;
            f32x4 bv = *(const f32x4*)(bias + h * NB + n);
            int col = (n >> 7) * 1024 + h * 128 + (n & 127);
            #pragma unroll
            for (int i = 0; i < 2; ++i) {
                u16x4 o;
                o[0] = f2bf(acc[i][j][0] + bv[0]);
                o[1] = f2bf(acc[i][j][1] + bv[1]);
                o[2] = f2bf(acc[i][j][2] + bv[2]);
                o[3] = f2bf(acc[i][j][3] + bv[3]);
                *(u16x4*)(C + (size_t)(tok0 + wm * 32 + i * 16 + rl) * crs + col) = o;
            }
        }
    }
}

// ---------------- K4b (wave-per-token, 16384 waves): LN over 3072 (bias pre-folded in gemm), gates.
__global__ void __launch_bounds__(256, 4) k4b_ln_gates(
        const ubf* __restrict__ h3, const float* __restrict__ g,
        const float* __restrict__ beta, ubf* __restrict__ fgl, float* __restrict__ igh) {
    int lane = threadIdx.x & 63;
    int tok  = blockIdx.x * 4 + (threadIdx.x >> 6);
    int c0 = 8 * lane;                    // col base within a part-plane (q=1 adds 512)
    const ubf* p = h3 + (size_t)tok * 3072;

    u16x8 raw[6];
    #pragma unroll
    for (int pp = 0; pp < 3; ++pp) {
        raw[pp * 2 + 0] = *(const u16x8*)(p + pp * 1024 + c0);
        raw[pp * 2 + 1] = *(const u16x8*)(p + pp * 1024 + 512 + c0);
    }
    float sum = 0.f, sq = 0.f;
    #pragma unroll
    for (int s = 0; s < 6; ++s) {
        #pragma unroll
        for (int j = 0; j < 8; ++j) {
            float a = bf2f((ubf)raw[s][j]);
            sum += a; sq = fmaf(a, a, sq);
        }
    }
    #pragma unroll
    for (int m = 32; m >= 1; m >>= 1) {
        sum += __shfl_xor(sum, m);
        sq  += __shfl_xor(sq, m);
    }
    float mu = sum * (1.f / 3072.f);
    float r  = rsqrtf(sq * (1.f / 3072.f) - mu * mu + LNEPS);

    int dd = c0 & 127;
    size_t ob = (size_t)tok * HD + c0;
    #pragma unroll
    for (int q = 0; q < 2; ++q) {
        int hq = (c0 + q * 512) >> 7;
        int gb = hq * 384 + dd;           // g_hid/beta_hid are [h][part][d]
        f32x4 gv[3][2], bv[3][2];
        #pragma unroll
        for (int pp = 0; pp < 3; ++pp) {
            gv[pp][0] = *(const f32x4*)(g + gb + pp * 128);
            gv[pp][1] = *(const f32x4*)(g + gb + pp * 128 + 4);
            bv[pp][0] = *(const f32x4*)(beta + gb + pp * 128);
            bv[pp][1] = *(const f32x4*)(beta + gb + pp * 128 + 4);
        }
        u16x8 fo;
        f32x4 io0, io1;
        #pragma unroll
        for (int j = 0; j < 8; ++j) {
            float ai = bf2f((ubf)raw[0 + q][j]);
            float af = bf2f((ubf)raw[2 + q][j]);
            float ah = bf2f((ubf)raw[4 + q][j]);
            float li = (ai - mu) * r * gv[0][j >> 2][j & 3] + bv[0][j >> 2][j & 3];
            float lf = (af - mu) * r * gv[1][j >> 2][j & 3] + bv[1][j >> 2][j & 3];
            float lh = (ah - mu) * r * gv[2][j >> 2][j & 3] + bv[2][j >> 2][j & 3];
            fo[j] = f2bf(lf);
            float v = fast_sigmoid(li) * fmaxf(lh, 0.f);
            if (j < 4) io0[j & 3] = v; else io1[j & 3] = v;
        }
        *(u16x8*)(fgl + ob + q * 512) = fo;
        *(f32x4*)(igh + ob + q * 512) = io0;
        *(f32x4*)(igh + ob + q * 512 + 4) = io1;
    }
}

// ---------------- K5a: per-chunk recurrence summary: P = prod f, L = local end value
__global__ void k5a_chunkrec(const ubf* __restrict__ fgl, const float* __restrict__ igh,
                             float* __restrict__ Pb, float* __restrict__ Lb) {
    int bid = blockIdx.x;                 // b*NC2*HH + c*HH + h
    int h = bid % HH;
    int c = (bid / HH) % NC2;
    int b = bid / (HH * NC2);
    int d = threadIdx.x;
    size_t base = (size_t)(b * SS + c * CS2) * HD + h * DOo + d;
    float P = 1.f, L = 0.f;
    for (int s = 0; s < CS2; ++s) {
        float f = 1.f / (1.f + expf(-bf2f(fgl[base + (size_t)s * HD])));
        float i = igh[base + (size_t)s * HD];
        L = f * L + i;
        P *= f;
    }
    int o = ((b * NC2 + c) * HH + h) * DOo + d;
    Pb[o] = P;
    Lb[o] = L;
}

// ---------------- K5b: serial carry across chunks (batch-loaded 8-deep)
__global__ void k5b_carry(const float* __restrict__ Pb, const float* __restrict__ Lb,
                          const float* __restrict__ init_cx, float* __restrict__ cIn) {
    int bid = blockIdx.x;                 // b*HH + h
    int h = bid % HH;
    int b = bid / HH;
    int d = threadIdx.x;
    float c = init_cx[h * DOo + d];
    for (int c0 = 0; c0 < NC2; c0 += 8) {
        float pv[8], lv[8];
        #pragma unroll
        for (int k = 0; k < 8; ++k) {
            int o = ((b * NC2 + c0 + k) * HH + h) * DOo + d;
            pv[k] = Pb[o];
            lv[k] = Lb[o];
        }
        #pragma unroll
        for (int k = 0; k < 8; ++k) {
            int o = ((b * NC2 + c0 + k) * HH + h) * DOo + d;
            cIn[o] = c;
            c = pv[k] * c + lv[k];
        }
    }
}

// ---------------- K5c: final in-chunk recurrence; writes cell as BF16 ONLY (fp32 cell dropped;
// og-gemm and k6b both consume the same bf16 rounding -> consistent, saves 134MB of traffic).
__global__ void k5c_cell(const ubf* __restrict__ fgl, const float* __restrict__ igh,
                         const float* __restrict__ cIn, ubf* __restrict__ cell_bf) {
    int bid = blockIdx.x;
    int h = bid % HH;
    int c = (bid / HH) % NC2;
    int b = bid / (HH * NC2);
    int d = threadIdx.x;
    size_t base = (size_t)(b * SS + c * CS2) * HD + h * DOo + d;
    int o = ((b * NC2 + c) * HH + h) * DOo + d;
    float cv = cIn[o];
    for (int s = 0; s < CS2; ++s) {
        float f = 1.f / (1.f + expf(-bf2f(fgl[base + (size_t)s * HD])));
        float i = igh[base + (size_t)s * HD];
        cv = f * cv + i;
        cell_bf[base + (size_t)s * HD] = f2bf(cv);
    }
}

// ---------------- K6b (wave-per-token): LN over 1024 (bias pre-folded in og gemm),
// sigmoid*cell -> out. cell now read as BF16 (2 x u16x8).
__global__ void __launch_bounds__(256, 4) k6b_ln_out(
        const ubf* __restrict__ ogr, const ubf* __restrict__ cell_bf,
        float* __restrict__ out, const float* __restrict__ g, const float* __restrict__ beta) {
    int lane = threadIdx.x & 63;
    int tok  = blockIdx.x * 4 + (threadIdx.x >> 6);
    int c0 = 8 * lane;
    size_t base = (size_t)tok * HD + c0;

    u16x8 og0 = *(const u16x8*)(ogr + base);
    u16x8 og1 = *(const u16x8*)(ogr + base + 512);
    u16x8 cb0 = *(const u16x8*)(cell_bf + base);
    u16x8 cb1 = *(const u16x8*)(cell_bf + base + 512);

    float sum = 0.f, sq = 0.f;
    #pragma unroll
    for (int j = 0; j < 8; ++j) {
        float a0 = bf2f((ubf)og0[j]);
        float a1 = bf2f((ubf)og1[j]);
        sum += a0 + a1;
        sq = fmaf(a0, a0, sq);
        sq = fmaf(a1, a1, sq);
    }
    #pragma unroll
    for (int m = 32; m >= 1; m >>= 1) {
        sum += __shfl_xor(sum, m);
        sq  += __shfl_xor(sq, m);
    }
    float mu = sum * (1.f / 1024.f);
    float r  = rsqrtf(sq * (1.f / 1024.f) - mu * mu + LNEPS);

    #pragma unroll
    for (int q = 0; q < 2; ++q) {
        f32x4 gv0 = *(const f32x4*)(g + q * 512 + c0);
        f32x4 gv1 = *(const f32x4*)(g + q * 512 + c0 + 4);
        f32x4 bv0 = *(const f32x4*)(beta + q * 512 + c0);
        f32x4 bv1 = *(const f32x4*)(beta + q * 512 + c0 + 4);
        f32x4 o0, o1;
        #pragma unroll
        for (int j = 0; j < 8; ++j) {
            float a = bf2f((ubf)(q ? og1[j] : og0[j]));
            float cl = bf2f((ubf)(q ? cb1[j] : cb0[j]));
            float gg = (j < 4) ? gv0[j & 3] : gv1[j & 3];
            float bb = (j < 4) ? bv0[j & 3] : bv1[j & 3];
            float lo = (a - mu) * r * gg + bb;
            float v = fast_sigmoid(lo) * cl;
            if (j < 4) o0[j & 3] = v; else o1[j & 3] = v;
        }
        *(f32x4*)(out + base + q * 512) = o0;
        *(f32x4*)(out + base + q * 512 + 4) = o1;
    }
}

extern "C" void kernel_launch(void* const* d_in, const int* in_sizes, int n_in,
                              void* d_out, int out_size, void* d_ws, size_t ws_size,
                              hipStream_t stream) {
    const float* heads_input = (const float*)d_in[0];
    const float* W_hid   = (const float*)d_in[1];
    const float* b_hid   = (const float*)d_in[2];
    const float* g_csum  = (const float*)d_in[3];
    const float* beta_csum = (const float*)d_in[4];
    const float* g_hid   = (const float*)d_in[5];
    const float* beta_hid = (const float*)d_in[6];
    const float* W_og    = (const float*)d_in[7];
    const float* b_og    = (const float*)d_in[8];
    const float* g_og    = (const float*)d_in[9];
    const float* beta_og = (const float*)d_in[10];
    const float* init_cx = (const float*)d_in[11];
    float* out = (float*)d_out;           // fp32 output, NTOK*HD elements; holds igh mid-pipe

    // workspace layout (~171.5 MB)
    char* ws = (char*)d_ws;
    ubf* in_bf   = (ubf*)ws;                                   // 33,554,432 B
    ubf* csln_bf = (ubf*)(ws + (size_t)33554432);              // 33,554,432 B (later fgl)
    ubf* big     = (ubf*)(ws + (size_t)67108864);              // 100,663,296 B
    float* chunk = (float*)big;   // 2MB, k1..k3 only; dead before gemm writes h3 here
    ubf* h3      = big;                                        // k4a w, k4b r
    ubf* cell_bf = big;                                        // k5c w, og-gemm + k6b r (h3 dead)
    ubf* og_bf   = big + (size_t)NTOK * HD;                    // og-gemm w, k6b r
    char* tail   = ws + (size_t)167772160;
    float* Pb    = (float*)tail;                               //   524,288 B
    float* Lb    = Pb + (size_t)BB * NC2 * HD;                 //   524,288 B
    float* cIn   = Lb + (size_t)BB * NC2 * HD;                 //   524,288 B
    ubf* Wt_hid  = (ubf*)(cIn + (size_t)BB * NC2 * HD);        // 1,572,864 B (packed)
    ubf* Wt_og   = Wt_hid + (size_t)HH * 384 * 256;            //   524,288 B (packed)
    ubf* fgl     = csln_bf;   // alias: csln consumed by gemm(k4a) before k4b writes fgl

    kwt_pack<<<HH * (384 >> 6) * 8, 256, 0, stream>>>(W_hid, Wt_hid, 384);
    kwt_pack<<<HH * (128 >> 6) * 8, 256, 0, stream>>>(W_og, Wt_og, 128);
    k1_chunksum<<<BB * HH * NC1, 128, 0, stream>>>(heads_input, chunk, in_bf);
    k2_chunkscan<<<BB * HH, 128, 0, stream>>>(chunk);
    k3_csum_ln<<<BB * NC1, 256, 0, stream>>>(heads_input, chunk, g_csum, beta_csum, csln_bf);
    gemm_h<384><<<(NTOK / 64) * HH, 256, 0, stream>>>(in_bf, csln_bf, Wt_hid, b_hid, h3);
    k4b_ln_gates<<<NTOK / 4, 256, 0, stream>>>(h3, g_hid, beta_hid, fgl, out);
    k5a_chunkrec<<<BB * NC2 * HH, 128, 0, stream>>>(fgl, out, Pb, Lb);
    k5b_carry<<<BB * HH, 128, 0, stream>>>(Pb, Lb, init_cx, cIn);
    k5c_cell<<<BB * NC2 * HH, 128, 0, stream>>>(fgl, out, cIn, cell_bf);
    gemm_h<128><<<(NTOK / 64) * HH, 256, 0, stream>>>(in_bf, cell_bf, Wt_og, b_og, og_bf);
    k6b_ln_out<<<NTOK / 4, 256, 0, stream>>>(og_bf, cell_bf, out, g_og, beta_og);
}

// Round 11
// 341.258 us; speedup vs baseline: 1.3051x; 1.1464x over previous
//
#include <hip/hip_runtime.h>
#include <math.h>

// Problem constants. Device dtypes: all 12 inputs fp32, OUTPUT fp32.
#define BB 4
#define SS 4096
#define HH 8
#define DI 128
#define DOo 128
#define HD 1024        // HH*DI
#define NTOK (BB*SS)   // 16384
#define LNEPS 1e-6f

// cumsum chunking
#define CS1 32
#define NC1 128        // SS/CS1
// recurrence chunking
#define CS2 64
#define NC2 64         // SS/CS2

typedef unsigned short ubf;   // bf16 bits
typedef __attribute__((ext_vector_type(8))) short    bf16x8;
typedef __attribute__((ext_vector_type(8))) unsigned short u16x8;
typedef __attribute__((ext_vector_type(4))) unsigned short u16x4;
typedef __attribute__((ext_vector_type(4))) float    f32x4;

__device__ __forceinline__ float bf2f(ubf x) {
    union { unsigned int u; float f; } v; v.u = ((unsigned int)x) << 16; return v.f;
}
__device__ __forceinline__ ubf f2bf(float f) {
    union { float f; unsigned int u; } v; v.f = f;
    unsigned int r = v.u + 0x7FFFu + ((v.u >> 16) & 1u);   // RNE
    return (ubf)(r >> 16);
}
__device__ __forceinline__ float fast_sigmoid(float x) {
    return __builtin_amdgcn_rcpf(1.f + __expf(-x));
}
// async global->LDS, 16B per lane; lds dest = wave-uniform base + lane*16, global src per-lane
__device__ __forceinline__ void gload16(const ubf* g, ubf* l) {
    __builtin_amdgcn_global_load_lds(
        (const __attribute__((address_space(1))) void*)g,
        (__attribute__((address_space(3))) void*)l, 16, 0, 0);
}

// ---------------- KWT_PACK: W[h][256][NB] fp32 -> Wtp in MFMA-fragment-linear order (bf16).
// Wtp[(((h*(NB/64)+ns)*8+ks)*4+j)*64+lane][8e]: a B-fragment load is base+lane*16B (1KB linear).
// n = ns*64+j*16+(lane&15), k = ks*32+(lane>>4)*8+e.  (v4-verified)
__global__ void kwt_pack(const float* __restrict__ W, ubf* __restrict__ Wtp, int NB) {
    int bid = blockIdx.x;                 // (h, ns, ks)
    int ks = bid & 7;
    int ns = (bid >> 3) % (NB >> 6);
    int h  = bid / (8 * (NB >> 6));
    int t = threadIdx.x;
    int j = t >> 6, lane = t & 63;
    int n  = ns * 64 + j * 16 + (lane & 15);
    int k0 = ks * 32 + (lane >> 4) * 8;
    u16x8 o;
    #pragma unroll
    for (int e = 0; e < 8; ++e)
        o[e] = f2bf(W[((size_t)h * 256 + k0 + e) * NB + n]);
    *(u16x8*)(Wtp + ((((size_t)(h * (NB >> 6) + ns) * 8 + ks) * 4 + j) * 64 + lane) * 8) = o;
}

// ---------------- K1: per-chunk sums along S for the cumsum + emit in as bf16
__global__ void k1_chunksum(const float* __restrict__ in, float* __restrict__ chunk,
                            ubf* __restrict__ in_bf) {
    int bid = blockIdx.x;                 // b*HH*NC1 + h*NC1 + c
    int c = bid % NC1;
    int h = (bid / NC1) % HH;
    int b = bid / (NC1 * HH);
    int d = threadIdx.x;                  // 0..127
    size_t base = (size_t)(b * SS + c * CS1) * HD + h * DI + d;
    float s = 0.f;
    for (int i = 0; i < CS1; ++i) {
        float v = in[base + (size_t)i * HD];
        in_bf[base + (size_t)i * HD] = f2bf(v);
        s += v;
    }
    chunk[((b * NC1 + c) * HH + h) * DI + d] = s;
}

// ---------------- K2: serial exclusive scan over chunks (in-place), batch-loaded 16-deep
__global__ void k2_chunkscan(float* __restrict__ chunk) {
    int bid = blockIdx.x;                 // b*HH + h
    int h = bid % HH;
    int b = bid / HH;
    int d = threadIdx.x;
    float run = 0.f;
    for (int c0 = 0; c0 < NC1; c0 += 16) {
        float v[16];
        #pragma unroll
        for (int k = 0; k < 16; ++k)
            v[k] = chunk[((b * NC1 + c0 + k) * HH + h) * DI + d];
        #pragma unroll
        for (int k = 0; k < 16; ++k) {
            int idx = ((b * NC1 + c0 + k) * HH + h) * DI + d;
            chunk[idx] = run;
            run += v[k];
        }
    }
}

// ---------------- K3 (v2): in-chunk exclusive cumsum + LN over 1024/token (CS1=32 iters).
__global__ void __launch_bounds__(256) k3_csum_ln(
        const float* __restrict__ in, const float* __restrict__ chunkpre,
        const float* __restrict__ g, const float* __restrict__ beta,
        ubf* __restrict__ out) {
    __shared__ float2 scr[2][4];
    int c = blockIdx.x % NC1;
    int b = blockIdx.x / NC1;
    int t = threadIdx.x;                  // 0..255
    int lane = t & 63, w = t >> 6;
    int d0 = t * 4;
    f32x4 run = *(const f32x4*)(chunkpre + (size_t)(b * NC1 + c) * HD + d0);
    f32x4 gg  = *(const f32x4*)(g + d0);
    f32x4 bb  = *(const f32x4*)(beta + d0);
    const float* pin = in + (size_t)(b * SS + c * CS1) * HD + d0;
    ubf* pout = out + (size_t)(b * SS + c * CS1) * HD + d0;

    f32x4 v = *(const f32x4*)(pin);
    for (int i = 0; i < CS1; ++i) {
        f32x4 cs = run;
        run += v;
        float s = cs[0] + cs[1] + cs[2] + cs[3];
        float q = cs[0]*cs[0] + cs[1]*cs[1] + cs[2]*cs[2] + cs[3]*cs[3];
        #pragma unroll
        for (int off = 32; off >= 1; off >>= 1) {
            s += __shfl_xor(s, off);
            q += __shfl_xor(q, off);
        }
        if (lane == 0) scr[i & 1][w] = make_float2(s, q);
        if (i + 1 < CS1) v = *(const f32x4*)(pin + (size_t)(i + 1) * HD);
        __syncthreads();
        float2 p0 = scr[i & 1][0], p1 = scr[i & 1][1];
        float2 p2 = scr[i & 1][2], p3 = scr[i & 1][3];
        float S = p0.x + p1.x + p2.x + p3.x;
        float Q = p0.y + p1.y + p2.y + p3.y;
        float mu = S * (1.f / 1024.f);
        float r = rsqrtf(Q * (1.f / 1024.f) - mu * mu + LNEPS);
        u16x4 o;
        #pragma unroll
        for (int e = 0; e < 4; ++e) o[e] = f2bf((cs[e] - mu) * r * gg[e] + bb[e]);
        *(u16x4*)(pout + (size_t)i * HD) = o;
    }
}

// ---------------- GEMM v9 (REVERT from v10: 128-tile measured 61.4 vs 64-tile 69.9).
// Full-K A-tile staged once (64KB, 1 barrier), barrier-free loop; full XOR swizzle both sides.
// Mappings R8/R9-verified: af r=(w&1)*64+i*16+rl, k=ks*32+kq*8; bf n=nt*128+(w>>1)*64+j*16+rl;
// mfma(bf,af); epilogue u16x4, col=(n>>7)*1024+h*128+(n&127).
template <int NB>
__global__ void __launch_bounds__(256, 2) gemm_h(
        const ubf* __restrict__ Ab0, const ubf* __restrict__ Ab1,
        const ubf* __restrict__ Wtp, const float* __restrict__ bias,
        ubf* __restrict__ C) {
    __shared__ __align__(16) ubf As[64 * 512];   // 64 KB, full-K A-tile
    constexpr int ntiles = NB >> 7;       // 3 (hid) or 1 (og)
    int t = threadIdx.x;
    int lane = t & 63, w = t >> 6;
    int h = blockIdx.x & 7;               // head == XCD round-robin
    int tok0 = (blockIdx.x >> 3) * 128;
    int crs = NB * HH;
    int rl = lane & 15, kq = lane >> 4;

    // ---- stage full-K A once (chunk-XOR preswizzled global source; linear DMA dest)
    {
        int rowi = lane >> 4;             // row within 4-row group
        #pragma unroll
        for (int q = 0; q < 16; ++q) {
            int bi = w * 16 + q;
            int rowgrp = bi >> 1, half = bi & 1;
            int row = rowgrp * 4 + rowi;
            int cg = (lane & 15) ^ rowi ^ ((rowgrp & 3) << 2);
            const ubf* src = (half ? Ab1 : Ab0)
                             + (size_t)(tok0 + row) * HD + h * DI + cg * 8;
            gload16(src, As + bi * 512);
        }
    }
    __syncthreads();   // the ONLY barrier

    const ubf* pWb = Wtp + ((size_t)h * (NB >> 6)) * 16384 + (size_t)lane * 8;

    #pragma unroll
    for (int nt = 0; nt < ntiles; ++nt) {
        int ns = nt * 2 + (w >> 1);
        // all B fragments of this nt up-front (32 x 1KB linear loads, L2-hot)
        bf16x8 bfr[8][4];
        #pragma unroll
        for (int ks = 0; ks < 8; ++ks)
            #pragma unroll
            for (int j = 0; j < 4; ++j)
                bfr[ks][j] = *(const bf16x8*)(pWb + (size_t)((ns * 8 + ks) * 4 + j) * 512);

        f32x4 acc[4][4];
        #pragma unroll
        for (int i = 0; i < 4; ++i)
            #pragma unroll
            for (int j = 0; j < 4; ++j) acc[i][j] = (f32x4){0.f, 0.f, 0.f, 0.f};

        #pragma unroll
        for (int ks = 0; ks < 8; ++ks) {
            int c = ks * 4 + kq;
            int chi = (c >> 4) * 512;     // half select (in ubf units: 1024B block /2)
            int clo = (((c & 15) ^ (rl & 3)) ^ (((rl >> 2) & 3) << 2)) * 8;
            bf16x8 af[4];
            #pragma unroll
            for (int i = 0; i < 4; ++i) {
                int r = (w & 1) * 64 + i * 16 + rl;
                af[i] = *(const bf16x8*)(As + ((r >> 2) * 2) * 512 + chi
                                            + (r & 3) * 128 + clo);
            }
            #pragma unroll
            for (int i = 0; i < 4; ++i)
                #pragma unroll
                for (int j = 0; j < 4; ++j)
                    acc[i][j] = __builtin_amdgcn_mfma_f32_16x16x32_bf16(bfr[ks][j], af[i], acc[i][j], 0, 0, 0);
        }

        // epilogue: n = nt*128+(w>>1)*64+j*16+kq*4+r ; token = tok0+(w&1)*64+i*16+rl
        int nq0 = nt * 128 + (w >> 1) * 64 + kq * 4;
        #pragma unroll
        for (int j = 0; j < 4; ++j) {
            int n = nq0 + j * 16;
            f32x4 bv = *(const f32x4*)(bias + h * NB + n);
            int col = (n >> 7) * 1024 + h * 128 + (n & 127);
            #pragma unroll
            for (int i = 0; i < 4; ++i) {
                u16x4 o;
                o[0] = f2bf(acc[i][j][0] + bv[0]);
                o[1] = f2bf(acc[i][j][1] + bv[1]);
                o[2] = f2bf(acc[i][j][2] + bv[2]);
                o[3] = f2bf(acc[i][j][3] + bv[3]);
                *(u16x4*)(C + (size_t)(tok0 + (w & 1) * 64 + i * 16 + rl) * crs + col) = o;
            }
        }
    }
}

// ---------------- K4b (wave-per-token, 16384 waves): LN over 3072 (bias pre-folded in gemm),
// gates. igh now written as BF16 (u16x8) -> half the write traffic; k5a/k5c read bf16.
__global__ void __launch_bounds__(256, 4) k4b_ln_gates(
        const ubf* __restrict__ h3, const float* __restrict__ g,
        const float* __restrict__ beta, ubf* __restrict__ fgl, ubf* __restrict__ igh) {
    int lane = threadIdx.x & 63;
    int tok  = blockIdx.x * 4 + (threadIdx.x >> 6);
    int c0 = 8 * lane;                    // col base within a part-plane (q=1 adds 512)
    const ubf* p = h3 + (size_t)tok * 3072;

    u16x8 raw[6];
    #pragma unroll
    for (int pp = 0; pp < 3; ++pp) {
        raw[pp * 2 + 0] = *(const u16x8*)(p + pp * 1024 + c0);
        raw[pp * 2 + 1] = *(const u16x8*)(p + pp * 1024 + 512 + c0);
    }
    float sum = 0.f, sq = 0.f;
    #pragma unroll
    for (int s = 0; s < 6; ++s) {
        #pragma unroll
        for (int j = 0; j < 8; ++j) {
            float a = bf2f((ubf)raw[s][j]);
            sum += a; sq = fmaf(a, a, sq);
        }
    }
    #pragma unroll
    for (int m = 32; m >= 1; m >>= 1) {
        sum += __shfl_xor(sum, m);
        sq  += __shfl_xor(sq, m);
    }
    float mu = sum * (1.f / 3072.f);
    float r  = rsqrtf(sq * (1.f / 3072.f) - mu * mu + LNEPS);

    int dd = c0 & 127;
    size_t ob = (size_t)tok * HD + c0;
    #pragma unroll
    for (int q = 0; q < 2; ++q) {
        int hq = (c0 + q * 512) >> 7;
        int gb = hq * 384 + dd;           // g_hid/beta_hid are [h][part][d]
        f32x4 gv[3][2], bv[3][2];
        #pragma unroll
        for (int pp = 0; pp < 3; ++pp) {
            gv[pp][0] = *(const f32x4*)(g + gb + pp * 128);
            gv[pp][1] = *(const f32x4*)(g + gb + pp * 128 + 4);
            bv[pp][0] = *(const f32x4*)(beta + gb + pp * 128);
            bv[pp][1] = *(const f32x4*)(beta + gb + pp * 128 + 4);
        }
        u16x8 fo, io;
        #pragma unroll
        for (int j = 0; j < 8; ++j) {
            float ai = bf2f((ubf)raw[0 + q][j]);
            float af = bf2f((ubf)raw[2 + q][j]);
            float ah = bf2f((ubf)raw[4 + q][j]);
            float li = (ai - mu) * r * gv[0][j >> 2][j & 3] + bv[0][j >> 2][j & 3];
            float lf = (af - mu) * r * gv[1][j >> 2][j & 3] + bv[1][j >> 2][j & 3];
            float lh = (ah - mu) * r * gv[2][j >> 2][j & 3] + bv[2][j >> 2][j & 3];
            fo[j] = f2bf(lf);
            io[j] = f2bf(fast_sigmoid(li) * fmaxf(lh, 0.f));
        }
        *(u16x8*)(fgl + ob + q * 512) = fo;
        *(u16x8*)(igh + ob + q * 512) = io;
    }
}

// ---------------- K5a: per-chunk recurrence summary: P = prod f, L = local end value (igh bf16)
__global__ void k5a_chunkrec(const ubf* __restrict__ fgl, const ubf* __restrict__ igh,
                             float* __restrict__ Pb, float* __restrict__ Lb) {
    int bid = blockIdx.x;                 // b*NC2*HH + c*HH + h
    int h = bid % HH;
    int c = (bid / HH) % NC2;
    int b = bid / (HH * NC2);
    int d = threadIdx.x;
    size_t base = (size_t)(b * SS + c * CS2) * HD + h * DOo + d;
    float P = 1.f, L = 0.f;
    for (int s = 0; s < CS2; ++s) {
        float f = fast_sigmoid(bf2f(fgl[base + (size_t)s * HD]));
        float i = bf2f(igh[base + (size_t)s * HD]);
        L = f * L + i;
        P *= f;
    }
    int o = ((b * NC2 + c) * HH + h) * DOo + d;
    Pb[o] = P;
    Lb[o] = L;
}

// ---------------- K5b: serial carry across chunks (batch-loaded 8-deep)
__global__ void k5b_carry(const float* __restrict__ Pb, const float* __restrict__ Lb,
                          const float* __restrict__ init_cx, float* __restrict__ cIn) {
    int bid = blockIdx.x;                 // b*HH + h
    int h = bid % HH;
    int b = bid / HH;
    int d = threadIdx.x;
    float c = init_cx[h * DOo + d];
    for (int c0 = 0; c0 < NC2; c0 += 8) {
        float pv[8], lv[8];
        #pragma unroll
        for (int k = 0; k < 8; ++k) {
            int o = ((b * NC2 + c0 + k) * HH + h) * DOo + d;
            pv[k] = Pb[o];
            lv[k] = Lb[o];
        }
        #pragma unroll
        for (int k = 0; k < 8; ++k) {
            int o = ((b * NC2 + c0 + k) * HH + h) * DOo + d;
            cIn[o] = c;
            c = pv[k] * c + lv[k];
        }
    }
}

// ---------------- K5c: final in-chunk recurrence; cell bf16 only (igh read as bf16)
__global__ void k5c_cell(const ubf* __restrict__ fgl, const ubf* __restrict__ igh,
                         const float* __restrict__ cIn, ubf* __restrict__ cell_bf) {
    int bid = blockIdx.x;
    int h = bid % HH;
    int c = (bid / HH) % NC2;
    int b = bid / (HH * NC2);
    int d = threadIdx.x;
    size_t base = (size_t)(b * SS + c * CS2) * HD + h * DOo + d;
    int o = ((b * NC2 + c) * HH + h) * DOo + d;
    float cv = cIn[o];
    for (int s = 0; s < CS2; ++s) {
        float f = fast_sigmoid(bf2f(fgl[base + (size_t)s * HD]));
        float i = bf2f(igh[base + (size_t)s * HD]);
        cv = f * cv + i;
        cell_bf[base + (size_t)s * HD] = f2bf(cv);
    }
}

// ---------------- K6b (wave-per-token): LN over 1024 (bias pre-folded in og gemm),
// sigmoid*cell -> out. cell read as BF16 (2 x u16x8).
__global__ void __launch_bounds__(256, 4) k6b_ln_out(
        const ubf* __restrict__ ogr, const ubf* __restrict__ cell_bf,
        float* __restrict__ out, const float* __restrict__ g, const float* __restrict__ beta) {
    int lane = threadIdx.x & 63;
    int tok  = blockIdx.x * 4 + (threadIdx.x >> 6);
    int c0 = 8 * lane;
    size_t base = (size_t)tok * HD + c0;

    u16x8 og0 = *(const u16x8*)(ogr + base);
    u16x8 og1 = *(const u16x8*)(ogr + base + 512);
    u16x8 cb0 = *(const u16x8*)(cell_bf + base);
    u16x8 cb1 = *(const u16x8*)(cell_bf + base + 512);

    float sum = 0.f, sq = 0.f;
    #pragma unroll
    for (int j = 0; j < 8; ++j) {
        float a0 = bf2f((ubf)og0[j]);
        float a1 = bf2f((ubf)og1[j]);
        sum += a0 + a1;
        sq = fmaf(a0, a0, sq);
        sq = fmaf(a1, a1, sq);
    }
    #pragma unroll
    for (int m = 32; m >= 1; m >>= 1) {
        sum += __shfl_xor(sum, m);
        sq  += __shfl_xor(sq, m);
    }
    float mu = sum * (1.f / 1024.f);
    float r  = rsqrtf(sq * (1.f / 1024.f) - mu * mu + LNEPS);

    #pragma unroll
    for (int q = 0; q < 2; ++q) {
        f32x4 gv0 = *(const f32x4*)(g + q * 512 + c0);
        f32x4 gv1 = *(const f32x4*)(g + q * 512 + c0 + 4);
        f32x4 bv0 = *(const f32x4*)(beta + q * 512 + c0);
        f32x4 bv1 = *(const f32x4*)(beta + q * 512 + c0 + 4);
        f32x4 o0, o1;
        #pragma unroll
        for (int j = 0; j < 8; ++j) {
            float a = bf2f((ubf)(q ? og1[j] : og0[j]));
            float cl = bf2f((ubf)(q ? cb1[j] : cb0[j]));
            float gg = (j < 4) ? gv0[j & 3] : gv1[j & 3];
            float bb = (j < 4) ? bv0[j & 3] : bv1[j & 3];
            float lo = (a - mu) * r * gg + bb;
            float v = fast_sigmoid(lo) * cl;
            if (j < 4) o0[j & 3] = v; else o1[j & 3] = v;
        }
        *(f32x4*)(out + base + q * 512) = o0;
        *(f32x4*)(out + base + q * 512 + 4) = o1;
    }
}

extern "C" void kernel_launch(void* const* d_in, const int* in_sizes, int n_in,
                              void* d_out, int out_size, void* d_ws, size_t ws_size,
                              hipStream_t stream) {
    const float* heads_input = (const float*)d_in[0];
    const float* W_hid   = (const float*)d_in[1];
    const float* b_hid   = (const float*)d_in[2];
    const float* g_csum  = (const float*)d_in[3];
    const float* beta_csum = (const float*)d_in[4];
    const float* g_hid   = (const float*)d_in[5];
    const float* beta_hid = (const float*)d_in[6];
    const float* W_og    = (const float*)d_in[7];
    const float* b_og    = (const float*)d_in[8];
    const float* g_og    = (const float*)d_in[9];
    const float* beta_og = (const float*)d_in[10];
    const float* init_cx = (const float*)d_in[11];
    float* out = (float*)d_out;           // fp32 output; first half doubles as igh_bf scratch

    // workspace layout (~172.5 MB)
    char* ws = (char*)d_ws;
    ubf* in_bf   = (ubf*)ws;                                   // 33,554,432 B
    ubf* csln_bf = (ubf*)(ws + (size_t)33554432);              // 33,554,432 B (later fgl)
    char* bigc   = ws + (size_t)67108864;                      // 100,663,296 B region
    ubf* big     = (ubf*)bigc;
    float* chunk = (float*)bigc;  // 2MB, k1..k3 only; dead before gemm writes h3 here
    ubf* h3      = big;                                        // hid-gemm w, k4b r (100MB)
    ubf* cell_bf = big;                                        // k5c w, og-gemm + k6b r (h3 dead)
    ubf* og_bf   = big + (size_t)NTOK * HD;                    // og-gemm w, k6b r (33.5-67MB)
    // Pb/Lb/cIn live at big+70MB (h3 dead when k5a writes; og/cell end at 67MB) — 3MB total
    float* Pb    = (float*)(bigc + (size_t)73400320);          // 1,048,576 B  (BB*NC2*HD fp32)
    float* Lb    = Pb + (size_t)BB * NC2 * HD;                 // 1,048,576 B
    float* cIn   = Lb + (size_t)BB * NC2 * HD;                 // 1,048,576 B
    char* tail   = ws + (size_t)167772160;
    ubf* Wt_hid  = (ubf*)tail;                                 // 1,572,864 B (packed)
    ubf* Wt_og   = Wt_hid + (size_t)HH * 384 * 256;            //   524,288 B (packed)
    ubf* fgl     = csln_bf;   // alias: csln consumed by hid-gemm before k4b writes fgl
    ubf* igh_bf  = (ubf*)out; // alias: igh dead before k6b writes fp32 out

    kwt_pack<<<HH * (384 >> 6) * 8, 256, 0, stream>>>(W_hid, Wt_hid, 384);
    kwt_pack<<<HH * (128 >> 6) * 8, 256, 0, stream>>>(W_og, Wt_og, 128);
    k1_chunksum<<<BB * HH * NC1, 128, 0, stream>>>(heads_input, chunk, in_bf);
    k2_chunkscan<<<BB * HH, 128, 0, stream>>>(chunk);
    k3_csum_ln<<<BB * NC1, 256, 0, stream>>>(heads_input, chunk, g_csum, beta_csum, csln_bf);
    gemm_h<384><<<(NTOK / 128) * HH, 256, 0, stream>>>(in_bf, csln_bf, Wt_hid, b_hid, h3);
    k4b_ln_gates<<<NTOK / 4, 256, 0, stream>>>(h3, g_hid, beta_hid, fgl, igh_bf);
    k5a_chunkrec<<<BB * NC2 * HH, 128, 0, stream>>>(fgl, igh_bf, Pb, Lb);
    k5b_carry<<<BB * HH, 128, 0, stream>>>(Pb, Lb, init_cx, cIn);
    k5c_cell<<<BB * NC2 * HH, 128, 0, stream>>>(fgl, igh_bf, cIn, cell_bf);
    gemm_h<128><<<(NTOK / 128) * HH, 256, 0, stream>>>(in_bf, cell_bf, Wt_og, b_og, og_bf);
    k6b_ln_out<<<NTOK / 4, 256, 0, stream>>>(og_bf, cell_bf, out, g_og, beta_og);
}